// Round 9
// baseline (4424.388 us; speedup 1.0000x reference)
//
#include <hip/hip_runtime.h>

typedef unsigned short u16;
typedef __attribute__((ext_vector_type(8))) short short8;
typedef __attribute__((ext_vector_type(4))) float float4v;

static constexpr int   kN    = 100000;   // nodes
static constexpr int   kE    = 200000;   // edges
static constexpr int   kEMB  = 300;
static constexpr int   kSA   = 304;      // feature row stride (elems)
static constexpr int   kKW1  = 320;      // W1T row stride (K padded)
static constexpr int   kNH   = 600;
static constexpr int   kNHP  = 608;
static constexpr int   kNP2  = 304;
static constexpr int   kLH1  = 616;      // LDS h1 row stride (bf16 elems)
static constexpr int   kG    = 5000;
static constexpr int   kL    = 5;
static constexpr float kEPS  = 1e-5f;

__device__ inline float bf2f(u16 u) {
    union { unsigned u32; float f; } v; v.u32 = ((unsigned)u) << 16; return v.f;
}
__device__ inline u16 f2bf(float f) {
    union { float f; unsigned u; } v; v.f = f;
    unsigned r = v.u + 0x7fff + ((v.u >> 16) & 1);
    return (u16)(r >> 16);
}
__device__ inline short8 load8(const u16* p) {
    return *reinterpret_cast<const short8*>(p);
}
__device__ inline float4v zed4() { float4v z = {0.f, 0.f, 0.f, 0.f}; return z; }
__device__ inline float gload(const void* p, long long i, int isf32) {
    if (isf32) return ((const float*)p)[i];
    return bf2f(((const u16*)p)[i]);
}
__device__ inline float pread(const void* p, size_t i, int f32p) {
    if (f32p) return ((const float*)p)[i];
    return bf2f(((const u16*)p)[i]);
}
__device__ inline void pwrite(void* p, size_t i, float v, int f32p) {
    if (f32p) ((float*)p)[i] = v;
    else      ((u16*)p)[i] = f2bf(v);
}

// ---- dtype detect: vote on W1 bit patterns --------------------------------
__global__ void detect_kernel(const u16* __restrict__ w1raw, int* flag) {
    if (threadIdx.x == 0 && blockIdx.x == 0) {
        int cnt = 0;
        for (int i = 0; i < 256; ++i) {
            int e = (w1raw[i] >> 7) & 0xFF;
            if (e >= 96 && e <= 126) ++cnt;
        }
        *flag = (cnt >= 200) ? 0 : 1;                // 0 = bf16 inputs, 1 = f32
    }
}

// ---- convert a float input to canonical f32 -------------------------------
__global__ void cvt_kernel(const void* __restrict__ src, float* __restrict__ dst,
                           int n, const int* __restrict__ flag) {
    int i = blockIdx.x * blockDim.x + threadIdx.x;
    if (i >= n) return;
    int isf = *flag;
    dst[i] = isf ? ((const float*)src)[i] : bf2f(((const u16*)src)[i]);
}

// ---- weight transpose + pad (bf16 out; writes every element) --------------
__global__ void w1t_kernel(const void* __restrict__ W1, u16* __restrict__ W1T,
                           const int* __restrict__ flag) {
    int idx = blockIdx.x * blockDim.x + threadIdx.x;
    const int per_layer = kNHP * kKW1;
    if (idx >= kL * per_layer) return;
    int isf = *flag;
    int l = idx / per_layer; int rem = idx - l * per_layer;
    int n = rem / kKW1; int k = rem - n * kKW1;
    u16 v = 0;
    if (n < kNH && k < kEMB)
        v = f2bf(gload(W1, (long long)l * kEMB * kNH + (long long)k * kNH + n, isf));
    W1T[idx] = v;
}
__global__ void w2t_kernel(const void* __restrict__ W2, u16* __restrict__ W2T,
                           const int* __restrict__ flag) {
    int idx = blockIdx.x * blockDim.x + threadIdx.x;
    const int per_layer = kNP2 * kNHP;
    if (idx >= kL * per_layer) return;
    int isf = *flag;
    int l = idx / per_layer; int rem = idx - l * per_layer;
    int n = rem / kNHP; int k = rem - n * kNHP;
    u16 v = 0;
    if (n < kEMB && k < kNH)
        v = f2bf(gload(W2, (long long)l * kNH * kEMB + (long long)k * kEMB + n, isf));
    W2T[idx] = v;
}

// ---- embedding: h = emb1[x0] + emb2[x1] -> plane --------------------------
__global__ void embed_kernel(const int* __restrict__ x,
                             const float* __restrict__ emb1,
                             const float* __restrict__ emb2,
                             void* __restrict__ h, int f32p) {
    int idx = blockIdx.x * blockDim.x + threadIdx.x;
    if (idx >= kN * kSA) return;
    int n = idx / kSA; int c = idx - n * kSA;
    float v = 0.f;
    if (c < kEMB) v = emb1[x[2 * n] * kEMB + c] + emb2[x[2 * n + 1] * kEMB + c];
    pwrite(h, idx, v, f32p);
}

// ---- CSR build ------------------------------------------------------------
__global__ void zero_int_kernel(int* p, int n) {
    int i = blockIdx.x * blockDim.x + threadIdx.x;
    if (i < n) p[i] = 0;
}
__global__ void zero_f32_kernel(float* p, int n) {
    int i = blockIdx.x * blockDim.x + threadIdx.x;
    if (i < n) p[i] = 0.f;
}
__global__ void count_kernel(const int* __restrict__ dst, int* row_ptr) {
    int e = blockIdx.x * blockDim.x + threadIdx.x;
    if (e < kE) atomicAdd(&row_ptr[1 + dst[e]], 1);
}
__global__ __launch_bounds__(1024) void scan_kernel(int* a, int n) {
    __shared__ int s[1024];
    __shared__ int carry;
    int t = threadIdx.x;
    if (t == 0) carry = 0;
    __syncthreads();
    for (int base = 0; base < n; base += 1024) {
        int i = base + t;
        s[t] = (i < n) ? a[i] : 0;
        __syncthreads();
        for (int off = 1; off < 1024; off <<= 1) {
            int v = (t >= off) ? s[t - off] : 0;
            __syncthreads();
            s[t] += v;
            __syncthreads();
        }
        if (i < n) a[i] = s[t] + carry;
        __syncthreads();
        if (t == 1023) carry += s[1023];
        __syncthreads();
    }
}
__global__ void scatter_kernel(const int* __restrict__ src, const int* __restrict__ dst,
                               const int* __restrict__ ea,
                               const int* __restrict__ row_ptr, int* cursor,
                               int* __restrict__ epack) {
    int e = blockIdx.x * blockDim.x + threadIdx.x;
    if (e >= kE) return;
    int d = dst[e];
    int pos = row_ptr[d] + atomicAdd(&cursor[d], 1);
    epack[pos] = src[e] | (ea[2 * e] << 20) | (ea[2 * e + 1] << 24);
}

// ---- aggregation with fused BN(+relu) input transform ---------------------
__global__ __launch_bounds__(256) void aggregate_kernel(
        const void* __restrict__ h, const int* __restrict__ row_ptr,
        const int* __restrict__ epack,
        const float* __restrict__ e1,    // [6][kEMB] layer slice (f32)
        const float* __restrict__ e2,    // [3][kEMB]
        const float* __restrict__ stats,
        const float* __restrict__ gam,
        const float* __restrict__ bet,
        void* __restrict__ agg, int mode, int f32p) {
    int wave = threadIdx.x >> 6;
    int lane = threadIdx.x & 63;
    int node = blockIdx.x * 4 + wave;
    if (node >= kN) return;

    float sc[5], sh[5], acc[5];
#pragma unroll
    for (int j = 0; j < 5; ++j) {
        int c = j * 64 + lane;
        sc[j] = 1.f; sh[j] = 0.f;
        if (mode && c < kEMB) {
            const float invM = 1.0f / kN;
            float mu = stats[c] * invM;
            float var = stats[kEMB + c] * invM - mu * mu;
            if (var < 0.f) var = 0.f;
            float rs = rsqrtf(var + kEPS);
            sc[j] = rs * gam[c];
            sh[j] = bet[c] - mu * sc[j];
        }
        acc[j] = 0.f;
        if (c < kEMB) {
            float hv = pread(h, (size_t)node * kSA + c, f32p) * sc[j] + sh[j];
            if (mode && hv < 0.f) hv = 0.f;
            acc[j] = hv + e1[c] + e2[c];             // self loop ea=(0,0)
        }
    }
    int s = row_ptr[node], e = row_ptr[node + 1];
    for (int i = s; i < e; ++i) {
        int p = epack[i];
        int srcn = p & 0xFFFFF;
        int a0 = (p >> 20) & 15;
        int a1 = (p >> 24) & 15;
#pragma unroll
        for (int j = 0; j < 5; ++j) {
            int c = j * 64 + lane;
            if (c < kEMB) {
                float w = pread(h, (size_t)srcn * kSA + c, f32p) * sc[j] + sh[j];
                if (mode && w < 0.f) w = 0.f;
                acc[j] += w + e1[a0 * kEMB + c] + e2[a1 * kEMB + c];
            }
        }
    }
#pragma unroll
    for (int j = 0; j < 5; ++j) {
        int c = j * 64 + lane;
        if (c < kSA)
            pwrite(agg, (size_t)node * kSA + c, (c < kEMB) ? acc[j] : 0.f, f32p);
    }
}

// ---- fused MLP: relu(A@W1+b1)@W2+b2 -> D ----------------------------------
// 256 thr / 4 waves per block, 32-ROW m-block (2 m-fragments per wave).
// r8 falsified the chain-latency theory: the binding constraint is the B-load
// stream (1:2 load:MFMA).  m-blocking 2x gives 2 B-loads -> 8 MFMAs (1:4) and
// halves total L2 B-traffic (3125 blocks x 759 KB).  kc order per acc is
// unchanged -> bit-identical results.  LDS 78,848 B -> 2 blocks/CU.
__global__ __launch_bounds__(256, 2) void mlp_kernel(
        const void* A, void* D,           // may alias (small-ws): no restrict
        const u16* __restrict__ B1T,      // [kNHP][kKW1] bf16, zero-padded
        const float* __restrict__ bias1,  // [kNH] f32
        const u16* __restrict__ B2T,      // [kNP2][kNHP] bf16, zero-padded
        const float* __restrict__ bias2,  // [kEMB] f32
        int f32p) {
    __shared__ u16 Thi[32 * kLH1];        // 39,424 B
    __shared__ u16 Tlo[32 * kLH1];        // 39,424 B
    int wave = threadIdx.x >> 6;
    int lane = threadIdx.x & 63;
    int mb = blockIdx.x;                  // 32-row block
    int r16 = lane & 15, quad = lane >> 4;

    // ---- load A fragments for m-tiles t=0,1 (rows mb*32 + t*16 + r16) ----
    short8 ahi[2][10], alo[2][10];
    short8 zed = {0, 0, 0, 0, 0, 0, 0, 0};
#pragma unroll
    for (int t = 0; t < 2; ++t) {
        if (f32p) {
            const float* Arow =
                (const float*)A + (size_t)(mb * 32 + t * 16 + r16) * kSA + quad * 8;
#pragma unroll
            for (int kc = 0; kc < 10; ++kc) {
                short8 h = zed, l = zed;
                if (kc < 9 || quad < 2) {
                    const float* pp = Arow + kc * 32;
#pragma unroll
                    for (int j = 0; j < 8; ++j) {
                        float xv = pp[j];
                        u16 hb = f2bf(xv);
                        float resid = xv - bf2f(hb);
                        h[j] = (short)hb;
                        l[j] = (short)f2bf(resid);
                    }
                }
                ahi[t][kc] = h; alo[t][kc] = l;
            }
        } else {
            const u16* Arow =
                (const u16*)A + (size_t)(mb * 32 + t * 16 + r16) * kSA + quad * 8;
#pragma unroll
            for (int kc = 0; kc < 9; ++kc) ahi[t][kc] = load8(Arow + kc * 32);
            ahi[t][9] = (quad < 2) ? load8(Arow + 9 * 32) : zed;
#pragma unroll
            for (int kc = 0; kc < 10; ++kc) alo[t][kc] = zed;
        }
    }

    // ---- GEMM1 -> relu -> LDS hi/lo (dual-nt, dual-m) ----
    auto epi1 = [&](int nt, int t, float4v acc) {
        int n = nt * 16 + r16;               // col = lane&15
        float bv = (n < kNH) ? bias1[n] : 0.f;
#pragma unroll
        for (int r = 0; r < 4; ++r) {        // row-in-tile = quad*4 + r
            float v = acc[r] + bv;
            if (v < 0.f) v = 0.f;
            u16 hb = 0, lb = 0;
            if (n < kNH) {
                hb = f2bf(v);
                lb = f2bf(v - bf2f(hb));
            }
            Thi[(t * 16 + quad * 4 + r) * kLH1 + n] = hb;
            Tlo[(t * 16 + quad * 4 + r) * kLH1 + n] = lb;
        }
    };
    for (int nt = wave; nt < 38; nt += 8) {
        int nt1 = nt + 4;
        int has1 = (nt1 < 38) ? 1 : 0;
        const u16* Bb0 = B1T + (nt * 16 + r16) * kKW1 + quad * 8;
        const u16* Bb1 = B1T + ((has1 ? nt1 : nt) * 16 + r16) * kKW1 + quad * 8;
        float4v a00 = zed4(), a01 = zed4(), a10 = zed4(), a11 = zed4();
#pragma unroll
        for (int kc = 0; kc < 10; ++kc) {
            short8 b0 = load8(Bb0 + kc * 32);
            short8 b1 = load8(Bb1 + kc * 32);
            a00 = __builtin_amdgcn_mfma_f32_16x16x32_bf16(ahi[0][kc], b0, a00, 0, 0, 0);
            a01 = __builtin_amdgcn_mfma_f32_16x16x32_bf16(ahi[0][kc], b1, a01, 0, 0, 0);
            a10 = __builtin_amdgcn_mfma_f32_16x16x32_bf16(ahi[1][kc], b0, a10, 0, 0, 0);
            a11 = __builtin_amdgcn_mfma_f32_16x16x32_bf16(ahi[1][kc], b1, a11, 0, 0, 0);
            if (f32p) {
                a00 = __builtin_amdgcn_mfma_f32_16x16x32_bf16(alo[0][kc], b0, a00, 0, 0, 0);
                a01 = __builtin_amdgcn_mfma_f32_16x16x32_bf16(alo[0][kc], b1, a01, 0, 0, 0);
                a10 = __builtin_amdgcn_mfma_f32_16x16x32_bf16(alo[1][kc], b0, a10, 0, 0, 0);
                a11 = __builtin_amdgcn_mfma_f32_16x16x32_bf16(alo[1][kc], b1, a11, 0, 0, 0);
            }
        }
        epi1(nt, 0, a00);
        epi1(nt, 1, a10);
        if (has1) { epi1(nt1, 0, a01); epi1(nt1, 1, a11); }
    }
    __syncthreads();

    // ---- GEMM2 (split A from LDS, dual-nt, dual-m) -> +bias -> D ----
    auto epi2 = [&](int nt, int t, float4v acc) {
        int n = nt * 16 + r16;
        if (n < kEMB) {
            float bv = bias2[n];
#pragma unroll
            for (int r = 0; r < 4; ++r) {
                int m = mb * 32 + t * 16 + quad * 4 + r;
                pwrite(D, (size_t)m * kSA + n, acc[r] + bv, f32p);
            }
        }
    };
    for (int nt = wave; nt < 19; nt += 8) {
        int nt1 = nt + 4;
        int has1 = (nt1 < 19) ? 1 : 0;
        const u16* Bb0 = B2T + (nt * 16 + r16) * kNHP + quad * 8;
        const u16* Bb1 = B2T + ((has1 ? nt1 : nt) * 16 + r16) * kNHP + quad * 8;
        float4v a00 = zed4(), a01 = zed4(), a10 = zed4(), a11 = zed4();
#pragma unroll
        for (int kc = 0; kc < 19; ++kc) {
            short8 ah0 = load8(Thi + r16 * kLH1 + kc * 32 + quad * 8);
            short8 al0 = load8(Tlo + r16 * kLH1 + kc * 32 + quad * 8);
            short8 ah1 = load8(Thi + (16 + r16) * kLH1 + kc * 32 + quad * 8);
            short8 al1 = load8(Tlo + (16 + r16) * kLH1 + kc * 32 + quad * 8);
            short8 b0 = load8(Bb0 + kc * 32);
            short8 b1 = load8(Bb1 + kc * 32);
            a00 = __builtin_amdgcn_mfma_f32_16x16x32_bf16(ah0, b0, a00, 0, 0, 0);
            a01 = __builtin_amdgcn_mfma_f32_16x16x32_bf16(ah0, b1, a01, 0, 0, 0);
            a10 = __builtin_amdgcn_mfma_f32_16x16x32_bf16(ah1, b0, a10, 0, 0, 0);
            a11 = __builtin_amdgcn_mfma_f32_16x16x32_bf16(ah1, b1, a11, 0, 0, 0);
            a00 = __builtin_amdgcn_mfma_f32_16x16x32_bf16(al0, b0, a00, 0, 0, 0);
            a01 = __builtin_amdgcn_mfma_f32_16x16x32_bf16(al0, b1, a01, 0, 0, 0);
            a10 = __builtin_amdgcn_mfma_f32_16x16x32_bf16(al1, b0, a10, 0, 0, 0);
            a11 = __builtin_amdgcn_mfma_f32_16x16x32_bf16(al1, b1, a11, 0, 0, 0);
        }
        epi2(nt, 0, a00);
        epi2(nt, 1, a10);
        if (has1) { epi2(nt1, 0, a01); epi2(nt1, 1, a11); }
    }
}

// ---- BN stats: column sums / sumsq ----------------------------------------
__global__ __launch_bounds__(256) void bn_stats_kernel(
        const void* __restrict__ H2, float* __restrict__ stats, int f32p) {
    int row0 = blockIdx.x * 128;
    for (int c = threadIdx.x; c < kEMB; c += 256) {
        float s = 0.f, q = 0.f;
        for (int r = 0; r < 128; ++r) {
            int row = row0 + r;
            if (row < kN) {
                float v = pread(H2, (size_t)row * kSA + c, f32p);
                s += v; q += v * v;
            }
        }
        atomicAdd(&stats[c], s);
        atomicAdd(&stats[kEMB + c], q);
    }
}

// ---- per-graph mean pool with fused final BN (no relu) --------------------
__device__ inline int lower_bound(const int* a, int n, int key) {
    int lo = 0, hi = n;
    while (lo < hi) { int mid = (lo + hi) >> 1; if (a[mid] < key) lo = mid + 1; else hi = mid; }
    return lo;
}
__global__ __launch_bounds__(64) void pool_kernel(const void* __restrict__ h2,
                                                  const int* __restrict__ batch,
                                                  const float* __restrict__ stats,
                                                  const float* __restrict__ gam,
                                                  const float* __restrict__ bet,
                                                  void* __restrict__ out,
                                                  const int* __restrict__ flag, int f32p) {
    int g = blockIdx.x;
    int lane = threadIdx.x;
    int isf = *flag;
    int start = lower_bound(batch, kN, g);
    int end = lower_bound(batch, kN, g + 1);
    int cnt = end - start;
    float inv = 1.0f / (float)(cnt > 0 ? cnt : 1);
    for (int c = lane; c < kEMB; c += 64) {
        const float invM = 1.0f / kN;
        float mu = stats[c] * invM;
        float var = stats[kEMB + c] * invM - mu * mu;
        if (var < 0.f) var = 0.f;
        float rs = rsqrtf(var + kEPS);
        float sc = rs * gam[c];
        float sh = bet[c] - mu * sc;
        float s = 0.f;
        for (int n = start; n < end; ++n)
            s += pread(h2, (size_t)n * kSA + c, f32p) * sc + sh;
        float v = s * inv;
        if (isf) ((float*)out)[g * kEMB + c] = v;
        else     ((u16*)out)[g * kEMB + c] = f2bf(v);
    }
}

// ===========================================================================
extern "C" void kernel_launch(void* const* d_in, const int* in_sizes, int n_in,
                              void* d_out, int out_size, void* d_ws, size_t ws_size,
                              hipStream_t stream) {
    const int* x          = (const int*)d_in[0];
    const int* edge_index = (const int*)d_in[1];
    const int* edge_attr  = (const int*)d_in[2];
    const int* batch      = (const int*)d_in[3];
    const void* x_emb1 = d_in[4];
    const void* x_emb2 = d_in[5];
    const void* e1raw  = d_in[6];
    const void* e2raw  = d_in[7];
    const void* W1     = d_in[8];
    const void* b1raw  = d_in[9];
    const void* W2     = d_in[10];
    const void* b2raw  = d_in[11];
    const void* gmraw  = d_in[12];
    const void* btraw  = d_in[13];

    const int* src = edge_index;
    const int* dst = edge_index + kE;

    // Path select: big ws -> f32 feature planes (high precision path).
    const int f32p = (ws_size >= (size_t)250000000) ? 1 : 0;
    const size_t esz = f32p ? 4 : 2;

    // ---- carve workspace (256B aligned) ----
    char* p = (char*)d_ws;
    size_t off = 0;
    auto carve = [&](size_t bytes) {
        void* r = p + off;
        off += (bytes + 255) & ~(size_t)255;
        return r;
    };
    void* plane0 = carve((size_t)kN * kSA * esz);
    void* plane1 = carve((size_t)kN * kSA * esz);
    u16* W1T     = (u16*)carve((size_t)kL * kNHP * kKW1 * 2);
    u16* W2T     = (u16*)carve((size_t)kL * kNP2 * kNHP * 2);
    int* row_ptr = (int*)carve((size_t)(kN + 1) * 4);
    int* cursor  = (int*)carve((size_t)kN * 4);
    int* epack   = (int*)carve((size_t)kE * 4);
    float* stats = (float*)carve(2 * kEMB * 4);
    int* flag    = (int*)carve(256);
    float* parf  = (float*)carve((size_t)57900 * 4);   // canonical f32 params

    float* emb1  = parf + 0;       // 36000
    float* emb2  = parf + 36000;   // 900
    float* e1    = parf + 36900;   // 9000
    float* e2    = parf + 45900;   // 4500
    float* b1    = parf + 50400;   // 3000
    float* b2    = parf + 53400;   // 1500
    float* gamma = parf + 54900;   // 1500
    float* beta  = parf + 56400;   // 1500

    // ---- dtype detect + canonicalize params to f32 ----
    detect_kernel<<<1, 64, 0, stream>>>((const u16*)W1, flag);
    cvt_kernel<<<(36000 + 255) / 256, 256, 0, stream>>>(x_emb1, emb1, 36000, flag);
    cvt_kernel<<<(900 + 255) / 256, 256, 0, stream>>>(x_emb2, emb2, 900, flag);
    cvt_kernel<<<(9000 + 255) / 256, 256, 0, stream>>>(e1raw, e1, 9000, flag);
    cvt_kernel<<<(4500 + 255) / 256, 256, 0, stream>>>(e2raw, e2, 4500, flag);
    cvt_kernel<<<(3000 + 255) / 256, 256, 0, stream>>>(b1raw, b1, 3000, flag);
    cvt_kernel<<<(1500 + 255) / 256, 256, 0, stream>>>(b2raw, b2, 1500, flag);
    cvt_kernel<<<(1500 + 255) / 256, 256, 0, stream>>>(gmraw, gamma, 1500, flag);
    cvt_kernel<<<(1500 + 255) / 256, 256, 0, stream>>>(btraw, beta, 1500, flag);

    // ---- weight transpose/pad (bf16) ----
    {
        int n1 = kL * kNHP * kKW1;
        w1t_kernel<<<(n1 + 255) / 256, 256, 0, stream>>>(W1, W1T, flag);
        int n2 = kL * kNP2 * kNHP;
        w2t_kernel<<<(n2 + 255) / 256, 256, 0, stream>>>(W2, W2T, flag);
    }

    // ---- embedding into plane0 ----
    embed_kernel<<<(kN * kSA + 255) / 256, 256, 0, stream>>>(x, emb1, emb2, plane0, f32p);

    // ---- CSR build ----
    zero_int_kernel<<<(kN + 1 + 255) / 256, 256, 0, stream>>>(row_ptr, kN + 1);
    zero_int_kernel<<<(kN + 255) / 256, 256, 0, stream>>>(cursor, kN);
    count_kernel<<<(kE + 255) / 256, 256, 0, stream>>>(dst, row_ptr);
    scan_kernel<<<1, 1024, 0, stream>>>(row_ptr + 1, kN);
    scatter_kernel<<<(kE + 255) / 256, 256, 0, stream>>>(src, dst, edge_attr, row_ptr,
                                                         cursor, epack);

    // ---- layers ----
    void* cur = plane0;
    void* agg = plane1;
    for (int l = 0; l < kL; ++l) {
        aggregate_kernel<<<(kN + 3) / 4, 256, 0, stream>>>(
            cur, row_ptr, epack, e1 + l * 6 * kEMB, e2 + l * 3 * kEMB,
            stats, gamma + (l > 0 ? (l - 1) : 0) * kEMB,
            beta + (l > 0 ? (l - 1) : 0) * kEMB, agg, (l > 0) ? 1 : 0, f32p);
        void* dout = f32p ? cur : agg;
        mlp_kernel<<<kN / 32, 256, 0, stream>>>(
            agg, dout, W1T + (size_t)l * kNHP * kKW1, b1 + l * kNH,
            W2T + (size_t)l * kNP2 * kNHP, b2 + l * kEMB, f32p);
        zero_f32_kernel<<<(2 * kEMB + 255) / 256, 256, 0, stream>>>(stats, 2 * kEMB);
        bn_stats_kernel<<<(kN + 127) / 128, 256, 0, stream>>>(dout, stats, f32p);
        cur = dout;
        agg = (cur == plane0) ? plane1 : plane0;
    }

    // ---- pooling with fused final BN ----
    pool_kernel<<<kG, 64, 0, stream>>>(cur, batch, stats, gamma + 4 * kEMB,
                                       beta + 4 * kEMB, d_out, flag, f32p);
}

// Round 10
// 4302.538 us; speedup vs baseline: 1.0283x; 1.0283x over previous
//
#include <hip/hip_runtime.h>

typedef unsigned short u16;
typedef __attribute__((ext_vector_type(8))) short short8;
typedef __attribute__((ext_vector_type(4))) float float4v;

static constexpr int   kN    = 100000;   // nodes
static constexpr int   kE    = 200000;   // edges
static constexpr int   kEMB  = 300;
static constexpr int   kSA   = 304;      // feature row stride (elems)
static constexpr int   kKW1  = 320;      // W1T row stride (K padded)
static constexpr int   kNH   = 600;
static constexpr int   kNHP  = 608;
static constexpr int   kNP2  = 304;
static constexpr int   kLH1  = 616;      // LDS h1 row stride (bf16 elems)
static constexpr int   kG    = 5000;
static constexpr int   kL    = 5;
static constexpr float kEPS  = 1e-5f;

__device__ inline float bf2f(u16 u) {
    union { unsigned u32; float f; } v; v.u32 = ((unsigned)u) << 16; return v.f;
}
__device__ inline u16 f2bf(float f) {
    union { float f; unsigned u; } v; v.f = f;
    unsigned r = v.u + 0x7fff + ((v.u >> 16) & 1);
    return (u16)(r >> 16);
}
__device__ inline short8 load8(const u16* p) {
    return *reinterpret_cast<const short8*>(p);
}
__device__ inline float4v zed4() { float4v z = {0.f, 0.f, 0.f, 0.f}; return z; }
__device__ inline float gload(const void* p, long long i, int isf32) {
    if (isf32) return ((const float*)p)[i];
    return bf2f(((const u16*)p)[i]);
}
__device__ inline float pread(const void* p, size_t i, int f32p) {
    if (f32p) return ((const float*)p)[i];
    return bf2f(((const u16*)p)[i]);
}
__device__ inline void pwrite(void* p, size_t i, float v, int f32p) {
    if (f32p) ((float*)p)[i] = v;
    else      ((u16*)p)[i] = f2bf(v);
}

// ---- dtype detect: vote on W1 bit patterns --------------------------------
__global__ void detect_kernel(const u16* __restrict__ w1raw, int* flag) {
    if (threadIdx.x == 0 && blockIdx.x == 0) {
        int cnt = 0;
        for (int i = 0; i < 256; ++i) {
            int e = (w1raw[i] >> 7) & 0xFF;
            if (e >= 96 && e <= 126) ++cnt;
        }
        *flag = (cnt >= 200) ? 0 : 1;                // 0 = bf16 inputs, 1 = f32
    }
}

// ---- convert a float input to canonical f32 -------------------------------
__global__ void cvt_kernel(const void* __restrict__ src, float* __restrict__ dst,
                           int n, const int* __restrict__ flag) {
    int i = blockIdx.x * blockDim.x + threadIdx.x;
    if (i >= n) return;
    int isf = *flag;
    dst[i] = isf ? ((const float*)src)[i] : bf2f(((const u16*)src)[i]);
}

// ---- weight transpose + pad (bf16 out; writes every element) --------------
__global__ void w1t_kernel(const void* __restrict__ W1, u16* __restrict__ W1T,
                           const int* __restrict__ flag) {
    int idx = blockIdx.x * blockDim.x + threadIdx.x;
    const int per_layer = kNHP * kKW1;
    if (idx >= kL * per_layer) return;
    int isf = *flag;
    int l = idx / per_layer; int rem = idx - l * per_layer;
    int n = rem / kKW1; int k = rem - n * kKW1;
    u16 v = 0;
    if (n < kNH && k < kEMB)
        v = f2bf(gload(W1, (long long)l * kEMB * kNH + (long long)k * kNH + n, isf));
    W1T[idx] = v;
}
__global__ void w2t_kernel(const void* __restrict__ W2, u16* __restrict__ W2T,
                           const int* __restrict__ flag) {
    int idx = blockIdx.x * blockDim.x + threadIdx.x;
    const int per_layer = kNP2 * kNHP;
    if (idx >= kL * per_layer) return;
    int isf = *flag;
    int l = idx / per_layer; int rem = idx - l * per_layer;
    int n = rem / kNHP; int k = rem - n * kNHP;
    u16 v = 0;
    if (n < kEMB && k < kNH)
        v = f2bf(gload(W2, (long long)l * kNH * kEMB + (long long)k * kEMB + n, isf));
    W2T[idx] = v;
}

// ---- embedding: h = emb1[x0] + emb2[x1] -> plane --------------------------
__global__ void embed_kernel(const int* __restrict__ x,
                             const float* __restrict__ emb1,
                             const float* __restrict__ emb2,
                             void* __restrict__ h, int f32p) {
    int idx = blockIdx.x * blockDim.x + threadIdx.x;
    if (idx >= kN * kSA) return;
    int n = idx / kSA; int c = idx - n * kSA;
    float v = 0.f;
    if (c < kEMB) v = emb1[x[2 * n] * kEMB + c] + emb2[x[2 * n + 1] * kEMB + c];
    pwrite(h, idx, v, f32p);
}

// ---- CSR build ------------------------------------------------------------
__global__ void zero_int_kernel(int* p, int n) {
    int i = blockIdx.x * blockDim.x + threadIdx.x;
    if (i < n) p[i] = 0;
}
__global__ void zero_f32_kernel(float* p, int n) {
    int i = blockIdx.x * blockDim.x + threadIdx.x;
    if (i < n) p[i] = 0.f;
}
__global__ void count_kernel(const int* __restrict__ dst, int* row_ptr) {
    int e = blockIdx.x * blockDim.x + threadIdx.x;
    if (e < kE) atomicAdd(&row_ptr[1 + dst[e]], 1);
}
__global__ __launch_bounds__(1024) void scan_kernel(int* a, int n) {
    __shared__ int s[1024];
    __shared__ int carry;
    int t = threadIdx.x;
    if (t == 0) carry = 0;
    __syncthreads();
    for (int base = 0; base < n; base += 1024) {
        int i = base + t;
        s[t] = (i < n) ? a[i] : 0;
        __syncthreads();
        for (int off = 1; off < 1024; off <<= 1) {
            int v = (t >= off) ? s[t - off] : 0;
            __syncthreads();
            s[t] += v;
            __syncthreads();
        }
        if (i < n) a[i] = s[t] + carry;
        __syncthreads();
        if (t == 1023) carry += s[1023];
        __syncthreads();
    }
}
__global__ void scatter_kernel(const int* __restrict__ src, const int* __restrict__ dst,
                               const int* __restrict__ ea,
                               const int* __restrict__ row_ptr, int* cursor,
                               int* __restrict__ epack) {
    int e = blockIdx.x * blockDim.x + threadIdx.x;
    if (e >= kE) return;
    int d = dst[e];
    int pos = row_ptr[d] + atomicAdd(&cursor[d], 1);
    epack[pos] = src[e] | (ea[2 * e] << 20) | (ea[2 * e + 1] << 24);
}

// ---- aggregation with fused BN(+relu) input transform ---------------------
__global__ __launch_bounds__(256) void aggregate_kernel(
        const void* __restrict__ h, const int* __restrict__ row_ptr,
        const int* __restrict__ epack,
        const float* __restrict__ e1,    // [6][kEMB] layer slice (f32)
        const float* __restrict__ e2,    // [3][kEMB]
        const float* __restrict__ stats,
        const float* __restrict__ gam,
        const float* __restrict__ bet,
        void* __restrict__ agg, int mode, int f32p) {
    int wave = threadIdx.x >> 6;
    int lane = threadIdx.x & 63;
    int node = blockIdx.x * 4 + wave;
    if (node >= kN) return;

    float sc[5], sh[5], acc[5];
#pragma unroll
    for (int j = 0; j < 5; ++j) {
        int c = j * 64 + lane;
        sc[j] = 1.f; sh[j] = 0.f;
        if (mode && c < kEMB) {
            const float invM = 1.0f / kN;
            float mu = stats[c] * invM;
            float var = stats[kEMB + c] * invM - mu * mu;
            if (var < 0.f) var = 0.f;
            float rs = rsqrtf(var + kEPS);
            sc[j] = rs * gam[c];
            sh[j] = bet[c] - mu * sc[j];
        }
        acc[j] = 0.f;
        if (c < kEMB) {
            float hv = pread(h, (size_t)node * kSA + c, f32p) * sc[j] + sh[j];
            if (mode && hv < 0.f) hv = 0.f;
            acc[j] = hv + e1[c] + e2[c];             // self loop ea=(0,0)
        }
    }
    int s = row_ptr[node], e = row_ptr[node + 1];
    for (int i = s; i < e; ++i) {
        int p = epack[i];
        int srcn = p & 0xFFFFF;
        int a0 = (p >> 20) & 15;
        int a1 = (p >> 24) & 15;
#pragma unroll
        for (int j = 0; j < 5; ++j) {
            int c = j * 64 + lane;
            if (c < kEMB) {
                float w = pread(h, (size_t)srcn * kSA + c, f32p) * sc[j] + sh[j];
                if (mode && w < 0.f) w = 0.f;
                acc[j] += w + e1[a0 * kEMB + c] + e2[a1 * kEMB + c];
            }
        }
    }
#pragma unroll
    for (int j = 0; j < 5; ++j) {
        int c = j * 64 + lane;
        if (c < kSA)
            pwrite(agg, (size_t)node * kSA + c, (c < kEMB) ? acc[j] : 0.f, f32p);
    }
}

// ---- fused MLP: relu(A@W1+b1)@W2+b2 -> D ----------------------------------
// 256 thr / 4 waves per block, 32-ROW m-block, dual-nt, dual-m (8 MFMAs per
// 2 B-loads).  r9 lesson: __launch_bounds__(256,2) capped the register file
// at 256/wave and SPILLED the 160-VGPR A-fragment set to scratch (FETCH/WRITE
// exploded 5x).  Fix: (256,1) -> 512-VGPR cap, and template on F32P so the
// dead bf16 path doesn't inflate the live set.  kc order per acc unchanged ->
// bit-identical results.
template <int F32P>
__global__ __launch_bounds__(256, 1) void mlp_kernel(
        const void* A, void* D,           // may alias (small-ws): no restrict
        const u16* __restrict__ B1T,      // [kNHP][kKW1] bf16, zero-padded
        const float* __restrict__ bias1,  // [kNH] f32
        const u16* __restrict__ B2T,      // [kNP2][kNHP] bf16, zero-padded
        const float* __restrict__ bias2) {// [kEMB] f32
    __shared__ u16 Thi[32 * kLH1];        // 39,424 B
    __shared__ u16 Tlo[32 * kLH1];        // 39,424 B
    int wave = threadIdx.x >> 6;
    int lane = threadIdx.x & 63;
    int mb = blockIdx.x;                  // 32-row block
    int r16 = lane & 15, quad = lane >> 4;

    // ---- load A fragments for m-tiles t=0,1 (rows mb*32 + t*16 + r16) ----
    short8 ahi[2][10], alo[2][10];
    short8 zed = {0, 0, 0, 0, 0, 0, 0, 0};
#pragma unroll
    for (int t = 0; t < 2; ++t) {
        if (F32P) {
            const float* Arow =
                (const float*)A + (size_t)(mb * 32 + t * 16 + r16) * kSA + quad * 8;
#pragma unroll
            for (int kc = 0; kc < 10; ++kc) {
                short8 h = zed, l = zed;
                if (kc < 9 || quad < 2) {
                    const float* pp = Arow + kc * 32;
#pragma unroll
                    for (int j = 0; j < 8; ++j) {
                        float xv = pp[j];
                        u16 hb = f2bf(xv);
                        float resid = xv - bf2f(hb);
                        h[j] = (short)hb;
                        l[j] = (short)f2bf(resid);
                    }
                }
                ahi[t][kc] = h; alo[t][kc] = l;
            }
        } else {
            const u16* Arow =
                (const u16*)A + (size_t)(mb * 32 + t * 16 + r16) * kSA + quad * 8;
#pragma unroll
            for (int kc = 0; kc < 9; ++kc) ahi[t][kc] = load8(Arow + kc * 32);
            ahi[t][9] = (quad < 2) ? load8(Arow + 9 * 32) : zed;
#pragma unroll
            for (int kc = 0; kc < 10; ++kc) alo[t][kc] = zed;
        }
    }

    // ---- GEMM1 -> relu -> LDS hi/lo (dual-nt, dual-m) ----
    auto epi1 = [&](int nt, int t, float4v acc) {
        int n = nt * 16 + r16;               // col = lane&15
        float bv = (n < kNH) ? bias1[n] : 0.f;
#pragma unroll
        for (int r = 0; r < 4; ++r) {        // row-in-tile = quad*4 + r
            float v = acc[r] + bv;
            if (v < 0.f) v = 0.f;
            u16 hb = 0, lb = 0;
            if (n < kNH) {
                hb = f2bf(v);
                lb = f2bf(v - bf2f(hb));
            }
            Thi[(t * 16 + quad * 4 + r) * kLH1 + n] = hb;
            Tlo[(t * 16 + quad * 4 + r) * kLH1 + n] = lb;
        }
    };
    for (int nt = wave; nt < 38; nt += 8) {
        int nt1 = nt + 4;
        int has1 = (nt1 < 38) ? 1 : 0;
        const u16* Bb0 = B1T + (nt * 16 + r16) * kKW1 + quad * 8;
        const u16* Bb1 = B1T + ((has1 ? nt1 : nt) * 16 + r16) * kKW1 + quad * 8;
        float4v a00 = zed4(), a01 = zed4(), a10 = zed4(), a11 = zed4();
#pragma unroll
        for (int kc = 0; kc < 10; ++kc) {
            short8 b0 = load8(Bb0 + kc * 32);
            short8 b1 = load8(Bb1 + kc * 32);
            a00 = __builtin_amdgcn_mfma_f32_16x16x32_bf16(ahi[0][kc], b0, a00, 0, 0, 0);
            a01 = __builtin_amdgcn_mfma_f32_16x16x32_bf16(ahi[0][kc], b1, a01, 0, 0, 0);
            a10 = __builtin_amdgcn_mfma_f32_16x16x32_bf16(ahi[1][kc], b0, a10, 0, 0, 0);
            a11 = __builtin_amdgcn_mfma_f32_16x16x32_bf16(ahi[1][kc], b1, a11, 0, 0, 0);
            if (F32P) {
                a00 = __builtin_amdgcn_mfma_f32_16x16x32_bf16(alo[0][kc], b0, a00, 0, 0, 0);
                a01 = __builtin_amdgcn_mfma_f32_16x16x32_bf16(alo[0][kc], b1, a01, 0, 0, 0);
                a10 = __builtin_amdgcn_mfma_f32_16x16x32_bf16(alo[1][kc], b0, a10, 0, 0, 0);
                a11 = __builtin_amdgcn_mfma_f32_16x16x32_bf16(alo[1][kc], b1, a11, 0, 0, 0);
            }
        }
        epi1(nt, 0, a00);
        epi1(nt, 1, a10);
        if (has1) { epi1(nt1, 0, a01); epi1(nt1, 1, a11); }
    }
    __syncthreads();

    // ---- GEMM2 (split A from LDS, dual-nt, dual-m) -> +bias -> D ----
    auto epi2 = [&](int nt, int t, float4v acc) {
        int n = nt * 16 + r16;
        if (n < kEMB) {
            float bv = bias2[n];
#pragma unroll
            for (int r = 0; r < 4; ++r) {
                int m = mb * 32 + t * 16 + quad * 4 + r;
                pwrite(D, (size_t)m * kSA + n, acc[r] + bv, F32P);
            }
        }
    };
    for (int nt = wave; nt < 19; nt += 8) {
        int nt1 = nt + 4;
        int has1 = (nt1 < 19) ? 1 : 0;
        const u16* Bb0 = B2T + (nt * 16 + r16) * kNHP + quad * 8;
        const u16* Bb1 = B2T + ((has1 ? nt1 : nt) * 16 + r16) * kNHP + quad * 8;
        float4v a00 = zed4(), a01 = zed4(), a10 = zed4(), a11 = zed4();
#pragma unroll
        for (int kc = 0; kc < 19; ++kc) {
            short8 ah0 = load8(Thi + r16 * kLH1 + kc * 32 + quad * 8);
            short8 al0 = load8(Tlo + r16 * kLH1 + kc * 32 + quad * 8);
            short8 ah1 = load8(Thi + (16 + r16) * kLH1 + kc * 32 + quad * 8);
            short8 al1 = load8(Tlo + (16 + r16) * kLH1 + kc * 32 + quad * 8);
            short8 b0 = load8(Bb0 + kc * 32);
            short8 b1 = load8(Bb1 + kc * 32);
            a00 = __builtin_amdgcn_mfma_f32_16x16x32_bf16(ah0, b0, a00, 0, 0, 0);
            a01 = __builtin_amdgcn_mfma_f32_16x16x32_bf16(ah0, b1, a01, 0, 0, 0);
            a10 = __builtin_amdgcn_mfma_f32_16x16x32_bf16(ah1, b0, a10, 0, 0, 0);
            a11 = __builtin_amdgcn_mfma_f32_16x16x32_bf16(ah1, b1, a11, 0, 0, 0);
            a00 = __builtin_amdgcn_mfma_f32_16x16x32_bf16(al0, b0, a00, 0, 0, 0);
            a01 = __builtin_amdgcn_mfma_f32_16x16x32_bf16(al0, b1, a01, 0, 0, 0);
            a10 = __builtin_amdgcn_mfma_f32_16x16x32_bf16(al1, b0, a10, 0, 0, 0);
            a11 = __builtin_amdgcn_mfma_f32_16x16x32_bf16(al1, b1, a11, 0, 0, 0);
        }
        epi2(nt, 0, a00);
        epi2(nt, 1, a10);
        if (has1) { epi2(nt1, 0, a01); epi2(nt1, 1, a11); }
    }
}

// ---- BN stats: column sums / sumsq ----------------------------------------
__global__ __launch_bounds__(256) void bn_stats_kernel(
        const void* __restrict__ H2, float* __restrict__ stats, int f32p) {
    int row0 = blockIdx.x * 128;
    for (int c = threadIdx.x; c < kEMB; c += 256) {
        float s = 0.f, q = 0.f;
        for (int r = 0; r < 128; ++r) {
            int row = row0 + r;
            if (row < kN) {
                float v = pread(H2, (size_t)row * kSA + c, f32p);
                s += v; q += v * v;
            }
        }
        atomicAdd(&stats[c], s);
        atomicAdd(&stats[kEMB + c], q);
    }
}

// ---- per-graph mean pool with fused final BN (no relu) --------------------
__device__ inline int lower_bound(const int* a, int n, int key) {
    int lo = 0, hi = n;
    while (lo < hi) { int mid = (lo + hi) >> 1; if (a[mid] < key) lo = mid + 1; else hi = mid; }
    return lo;
}
__global__ __launch_bounds__(64) void pool_kernel(const void* __restrict__ h2,
                                                  const int* __restrict__ batch,
                                                  const float* __restrict__ stats,
                                                  const float* __restrict__ gam,
                                                  const float* __restrict__ bet,
                                                  void* __restrict__ out,
                                                  const int* __restrict__ flag, int f32p) {
    int g = blockIdx.x;
    int lane = threadIdx.x;
    int isf = *flag;
    int start = lower_bound(batch, kN, g);
    int end = lower_bound(batch, kN, g + 1);
    int cnt = end - start;
    float inv = 1.0f / (float)(cnt > 0 ? cnt : 1);
    for (int c = lane; c < kEMB; c += 64) {
        const float invM = 1.0f / kN;
        float mu = stats[c] * invM;
        float var = stats[kEMB + c] * invM - mu * mu;
        if (var < 0.f) var = 0.f;
        float rs = rsqrtf(var + kEPS);
        float sc = rs * gam[c];
        float sh = bet[c] - mu * sc;
        float s = 0.f;
        for (int n = start; n < end; ++n)
            s += pread(h2, (size_t)n * kSA + c, f32p) * sc + sh;
        float v = s * inv;
        if (isf) ((float*)out)[g * kEMB + c] = v;
        else     ((u16*)out)[g * kEMB + c] = f2bf(v);
    }
}

// ===========================================================================
extern "C" void kernel_launch(void* const* d_in, const int* in_sizes, int n_in,
                              void* d_out, int out_size, void* d_ws, size_t ws_size,
                              hipStream_t stream) {
    const int* x          = (const int*)d_in[0];
    const int* edge_index = (const int*)d_in[1];
    const int* edge_attr  = (const int*)d_in[2];
    const int* batch      = (const int*)d_in[3];
    const void* x_emb1 = d_in[4];
    const void* x_emb2 = d_in[5];
    const void* e1raw  = d_in[6];
    const void* e2raw  = d_in[7];
    const void* W1     = d_in[8];
    const void* b1raw  = d_in[9];
    const void* W2     = d_in[10];
    const void* b2raw  = d_in[11];
    const void* gmraw  = d_in[12];
    const void* btraw  = d_in[13];

    const int* src = edge_index;
    const int* dst = edge_index + kE;

    // Path select: big ws -> f32 feature planes (high precision path).
    const int f32p = (ws_size >= (size_t)250000000) ? 1 : 0;
    const size_t esz = f32p ? 4 : 2;

    // ---- carve workspace (256B aligned) ----
    char* p = (char*)d_ws;
    size_t off = 0;
    auto carve = [&](size_t bytes) {
        void* r = p + off;
        off += (bytes + 255) & ~(size_t)255;
        return r;
    };
    void* plane0 = carve((size_t)kN * kSA * esz);
    void* plane1 = carve((size_t)kN * kSA * esz);
    u16* W1T     = (u16*)carve((size_t)kL * kNHP * kKW1 * 2);
    u16* W2T     = (u16*)carve((size_t)kL * kNP2 * kNHP * 2);
    int* row_ptr = (int*)carve((size_t)(kN + 1) * 4);
    int* cursor  = (int*)carve((size_t)kN * 4);
    int* epack   = (int*)carve((size_t)kE * 4);
    float* stats = (float*)carve(2 * kEMB * 4);
    int* flag    = (int*)carve(256);
    float* parf  = (float*)carve((size_t)57900 * 4);   // canonical f32 params

    float* emb1  = parf + 0;       // 36000
    float* emb2  = parf + 36000;   // 900
    float* e1    = parf + 36900;   // 9000
    float* e2    = parf + 45900;   // 4500
    float* b1    = parf + 50400;   // 3000
    float* b2    = parf + 53400;   // 1500
    float* gamma = parf + 54900;   // 1500
    float* beta  = parf + 56400;   // 1500

    // ---- dtype detect + canonicalize params to f32 ----
    detect_kernel<<<1, 64, 0, stream>>>((const u16*)W1, flag);
    cvt_kernel<<<(36000 + 255) / 256, 256, 0, stream>>>(x_emb1, emb1, 36000, flag);
    cvt_kernel<<<(900 + 255) / 256, 256, 0, stream>>>(x_emb2, emb2, 900, flag);
    cvt_kernel<<<(9000 + 255) / 256, 256, 0, stream>>>(e1raw, e1, 9000, flag);
    cvt_kernel<<<(4500 + 255) / 256, 256, 0, stream>>>(e2raw, e2, 4500, flag);
    cvt_kernel<<<(3000 + 255) / 256, 256, 0, stream>>>(b1raw, b1, 3000, flag);
    cvt_kernel<<<(1500 + 255) / 256, 256, 0, stream>>>(b2raw, b2, 1500, flag);
    cvt_kernel<<<(1500 + 255) / 256, 256, 0, stream>>>(gmraw, gamma, 1500, flag);
    cvt_kernel<<<(1500 + 255) / 256, 256, 0, stream>>>(btraw, beta, 1500, flag);

    // ---- weight transpose/pad (bf16) ----
    {
        int n1 = kL * kNHP * kKW1;
        w1t_kernel<<<(n1 + 255) / 256, 256, 0, stream>>>(W1, W1T, flag);
        int n2 = kL * kNP2 * kNHP;
        w2t_kernel<<<(n2 + 255) / 256, 256, 0, stream>>>(W2, W2T, flag);
    }

    // ---- embedding into plane0 ----
    embed_kernel<<<(kN * kSA + 255) / 256, 256, 0, stream>>>(x, emb1, emb2, plane0, f32p);

    // ---- CSR build ----
    zero_int_kernel<<<(kN + 1 + 255) / 256, 256, 0, stream>>>(row_ptr, kN + 1);
    zero_int_kernel<<<(kN + 255) / 256, 256, 0, stream>>>(cursor, kN);
    count_kernel<<<(kE + 255) / 256, 256, 0, stream>>>(dst, row_ptr);
    scan_kernel<<<1, 1024, 0, stream>>>(row_ptr + 1, kN);
    scatter_kernel<<<(kE + 255) / 256, 256, 0, stream>>>(src, dst, edge_attr, row_ptr,
                                                         cursor, epack);

    // ---- layers ----
    void* cur = plane0;
    void* agg = plane1;
    for (int l = 0; l < kL; ++l) {
        aggregate_kernel<<<(kN + 3) / 4, 256, 0, stream>>>(
            cur, row_ptr, epack, e1 + l * 6 * kEMB, e2 + l * 3 * kEMB,
            stats, gamma + (l > 0 ? (l - 1) : 0) * kEMB,
            beta + (l > 0 ? (l - 1) : 0) * kEMB, agg, (l > 0) ? 1 : 0, f32p);
        void* dout = f32p ? cur : agg;
        if (f32p)
            mlp_kernel<1><<<kN / 32, 256, 0, stream>>>(
                agg, dout, W1T + (size_t)l * kNHP * kKW1, b1 + l * kNH,
                W2T + (size_t)l * kNP2 * kNHP, b2 + l * kEMB);
        else
            mlp_kernel<0><<<kN / 32, 256, 0, stream>>>(
                agg, dout, W1T + (size_t)l * kNHP * kKW1, b1 + l * kNH,
                W2T + (size_t)l * kNP2 * kNHP, b2 + l * kEMB);
        zero_f32_kernel<<<(2 * kEMB + 255) / 256, 256, 0, stream>>>(stats, 2 * kEMB);
        bn_stats_kernel<<<(kN + 127) / 128, 256, 0, stream>>>(dout, stats, f32p);
        cur = dout;
        agg = (cur == plane0) ? plane1 : plane0;
    }

    // ---- pooling with fused final BN ----
    pool_kernel<<<kG, 64, 0, stream>>>(cur, batch, stats, gamma + 4 * kEMB,
                                       beta + 4 * kEMB, d_out, flag, f32p);
}

// Round 11
// 2964.464 us; speedup vs baseline: 1.4925x; 1.4514x over previous
//
#include <hip/hip_runtime.h>

typedef unsigned short u16;
typedef __attribute__((ext_vector_type(8))) short short8;
typedef __attribute__((ext_vector_type(4))) float float4v;

static constexpr int   kN    = 100000;   // nodes
static constexpr int   kE    = 200000;   // edges
static constexpr int   kEMB  = 300;
static constexpr int   kSA   = 304;      // feature row stride (elems)
static constexpr int   kKW1  = 320;      // W1T row stride (K padded)
static constexpr int   kNH   = 600;
static constexpr int   kNHP  = 608;
static constexpr int   kNP2  = 304;
static constexpr int   kG    = 5000;
static constexpr int   kL    = 5;
static constexpr float kEPS  = 1e-5f;

// mlp pipeline LDS strides (padded for bank spread, 16B-aligned rows)
static constexpr int   kSB1  = 328;      // B1 slice row stride (u16)
static constexpr int   kSB2  = 40;       // B2 slice row stride (u16)
static constexpr int   kSSC  = 40;       // transpose scratch row stride (u16)

__device__ inline float bf2f(u16 u) {
    union { unsigned u32; float f; } v; v.u32 = ((unsigned)u) << 16; return v.f;
}
__device__ inline u16 f2bf(float f) {
    union { float f; unsigned u; } v; v.f = f;
    unsigned r = v.u + 0x7fff + ((v.u >> 16) & 1);
    return (u16)(r >> 16);
}
__device__ inline short8 load8(const u16* p) {
    return *reinterpret_cast<const short8*>(p);
}
__device__ inline void store8(u16* p, short8 v) {
    *reinterpret_cast<short8*>(p) = v;
}
__device__ inline float4v zed4() { float4v z = {0.f, 0.f, 0.f, 0.f}; return z; }
__device__ inline float gload(const void* p, long long i, int isf32) {
    if (isf32) return ((const float*)p)[i];
    return bf2f(((const u16*)p)[i]);
}
__device__ inline float pread(const void* p, size_t i, int f32p) {
    if (f32p) return ((const float*)p)[i];
    return bf2f(((const u16*)p)[i]);
}
__device__ inline void pwrite(void* p, size_t i, float v, int f32p) {
    if (f32p) ((float*)p)[i] = v;
    else      ((u16*)p)[i] = f2bf(v);
}

// ---- dtype detect: vote on W1 bit patterns --------------------------------
__global__ void detect_kernel(const u16* __restrict__ w1raw, int* flag) {
    if (threadIdx.x == 0 && blockIdx.x == 0) {
        int cnt = 0;
        for (int i = 0; i < 256; ++i) {
            int e = (w1raw[i] >> 7) & 0xFF;
            if (e >= 96 && e <= 126) ++cnt;
        }
        *flag = (cnt >= 200) ? 0 : 1;                // 0 = bf16 inputs, 1 = f32
    }
}

// ---- convert a float input to canonical f32 -------------------------------
__global__ void cvt_kernel(const void* __restrict__ src, float* __restrict__ dst,
                           int n, const int* __restrict__ flag) {
    int i = blockIdx.x * blockDim.x + threadIdx.x;
    if (i >= n) return;
    int isf = *flag;
    dst[i] = isf ? ((const float*)src)[i] : bf2f(((const u16*)src)[i]);
}

// ---- weight transpose + pad (bf16 out; writes every element) --------------
__global__ void w1t_kernel(const void* __restrict__ W1, u16* __restrict__ W1T,
                           const int* __restrict__ flag) {
    int idx = blockIdx.x * blockDim.x + threadIdx.x;
    const int per_layer = kNHP * kKW1;
    if (idx >= kL * per_layer) return;
    int isf = *flag;
    int l = idx / per_layer; int rem = idx - l * per_layer;
    int n = rem / kKW1; int k = rem - n * kKW1;
    u16 v = 0;
    if (n < kNH && k < kEMB)
        v = f2bf(gload(W1, (long long)l * kEMB * kNH + (long long)k * kNH + n, isf));
    W1T[idx] = v;
}
__global__ void w2t_kernel(const void* __restrict__ W2, u16* __restrict__ W2T,
                           const int* __restrict__ flag) {
    int idx = blockIdx.x * blockDim.x + threadIdx.x;
    const int per_layer = kNP2 * kNHP;
    if (idx >= kL * per_layer) return;
    int isf = *flag;
    int l = idx / per_layer; int rem = idx - l * per_layer;
    int n = rem / kNHP; int k = rem - n * kNHP;
    u16 v = 0;
    if (n < kEMB && k < kNH)
        v = f2bf(gload(W2, (long long)l * kNH * kEMB + (long long)k * kEMB + n, isf));
    W2T[idx] = v;
}

// ---- embedding: h = emb1[x0] + emb2[x1] -> plane --------------------------
__global__ void embed_kernel(const int* __restrict__ x,
                             const float* __restrict__ emb1,
                             const float* __restrict__ emb2,
                             void* __restrict__ h, int f32p) {
    int idx = blockIdx.x * blockDim.x + threadIdx.x;
    if (idx >= kN * kSA) return;
    int n = idx / kSA; int c = idx - n * kSA;
    float v = 0.f;
    if (c < kEMB) v = emb1[x[2 * n] * kEMB + c] + emb2[x[2 * n + 1] * kEMB + c];
    pwrite(h, idx, v, f32p);
}

// ---- CSR build ------------------------------------------------------------
__global__ void zero_int_kernel(int* p, int n) {
    int i = blockIdx.x * blockDim.x + threadIdx.x;
    if (i < n) p[i] = 0;
}
__global__ void zero_f32_kernel(float* p, int n) {
    int i = blockIdx.x * blockDim.x + threadIdx.x;
    if (i < n) p[i] = 0.f;
}
__global__ void count_kernel(const int* __restrict__ dst, int* row_ptr) {
    int e = blockIdx.x * blockDim.x + threadIdx.x;
    if (e < kE) atomicAdd(&row_ptr[1 + dst[e]], 1);
}
__global__ __launch_bounds__(1024) void scan_kernel(int* a, int n) {
    __shared__ int s[1024];
    __shared__ int carry;
    int t = threadIdx.x;
    if (t == 0) carry = 0;
    __syncthreads();
    for (int base = 0; base < n; base += 1024) {
        int i = base + t;
        s[t] = (i < n) ? a[i] : 0;
        __syncthreads();
        for (int off = 1; off < 1024; off <<= 1) {
            int v = (t >= off) ? s[t - off] : 0;
            __syncthreads();
            s[t] += v;
            __syncthreads();
        }
        if (i < n) a[i] = s[t] + carry;
        __syncthreads();
        if (t == 1023) carry += s[1023];
        __syncthreads();
    }
}
__global__ void scatter_kernel(const int* __restrict__ src, const int* __restrict__ dst,
                               const int* __restrict__ ea,
                               const int* __restrict__ row_ptr, int* cursor,
                               int* __restrict__ epack) {
    int e = blockIdx.x * blockDim.x + threadIdx.x;
    if (e >= kE) return;
    int d = dst[e];
    int pos = row_ptr[d] + atomicAdd(&cursor[d], 1);
    epack[pos] = src[e] | (ea[2 * e] << 20) | (ea[2 * e + 1] << 24);
}

// ---- aggregation with fused BN(+relu) input transform ---------------------
__global__ __launch_bounds__(256) void aggregate_kernel(
        const void* __restrict__ h, const int* __restrict__ row_ptr,
        const int* __restrict__ epack,
        const float* __restrict__ e1,    // [6][kEMB] layer slice (f32)
        const float* __restrict__ e2,    // [3][kEMB]
        const float* __restrict__ stats,
        const float* __restrict__ gam,
        const float* __restrict__ bet,
        void* __restrict__ agg, int mode, int f32p) {
    int wave = threadIdx.x >> 6;
    int lane = threadIdx.x & 63;
    int node = blockIdx.x * 4 + wave;
    if (node >= kN) return;

    float sc[5], sh[5], acc[5];
#pragma unroll
    for (int j = 0; j < 5; ++j) {
        int c = j * 64 + lane;
        sc[j] = 1.f; sh[j] = 0.f;
        if (mode && c < kEMB) {
            const float invM = 1.0f / kN;
            float mu = stats[c] * invM;
            float var = stats[kEMB + c] * invM - mu * mu;
            if (var < 0.f) var = 0.f;
            float rs = rsqrtf(var + kEPS);
            sc[j] = rs * gam[c];
            sh[j] = bet[c] - mu * sc[j];
        }
        acc[j] = 0.f;
        if (c < kEMB) {
            float hv = pread(h, (size_t)node * kSA + c, f32p) * sc[j] + sh[j];
            if (mode && hv < 0.f) hv = 0.f;
            acc[j] = hv + e1[c] + e2[c];             // self loop ea=(0,0)
        }
    }
    int s = row_ptr[node], e = row_ptr[node + 1];
    for (int i = s; i < e; ++i) {
        int p = epack[i];
        int srcn = p & 0xFFFFF;
        int a0 = (p >> 20) & 15;
        int a1 = (p >> 24) & 15;
#pragma unroll
        for (int j = 0; j < 5; ++j) {
            int c = j * 64 + lane;
            if (c < kEMB) {
                float w = pread(h, (size_t)srcn * kSA + c, f32p) * sc[j] + sh[j];
                if (mode && w < 0.f) w = 0.f;
                acc[j] += w + e1[a0 * kEMB + c] + e2[a1 * kEMB + c];
            }
        }
    }
#pragma unroll
    for (int j = 0; j < 5; ++j) {
        int c = j * 64 + lane;
        if (c < kSA)
            pwrite(agg, (size_t)node * kSA + c, (c < kEMB) ? acc[j] : 0.f, f32p);
    }
}

// ---- fused MLP, k-slice pipeline: relu(A@W1+b1)@W2+b2 -> D ----------------
// 512 thr / 8 waves per block, 128 rows.  GEMM2's k-dim == GEMM1's n-dim, so
// process h1 in 32-col slices: stage B1-pair + B2-slice in LDS (shared by all
// 8 waves -> 4x fewer global B loads than r10), GEMM1 the slice, transpose
// C->A layout through 2.5KB wave-private LDS scratch, accumulate GEMM2 into
// persistent registers (19 x float4).  Bulk h1 LDS is GONE -> T/W plateau
// (r8==r10==1130 loads/resident-wave) broken.  Per-acc MFMA order (kc-major,
// hi-then-lo) is unchanged -> bit-identical to r8/r10 output.
template <int F32P>
__global__ __launch_bounds__(512, 2) void mlp_kernel(
        const void* A, void* D,           // may alias (small-ws): no restrict
        const u16* __restrict__ B1T,      // [kNHP][kKW1] bf16, zero-padded
        const float* __restrict__ bias1,  // [kNH] f32
        const u16* __restrict__ B2T,      // [kNP2][kNHP] bf16, zero-padded
        const float* __restrict__ bias2) {// [kEMB] f32
    __shared__ u16 LB1[32 * kSB1];           // 20,992 B : B1T rows [32s,32s+32)
    __shared__ u16 LB2[304 * kSB2];          // 24,320 B : B2T cols [32s,32s+32)
    __shared__ u16 LSC[8][2][16 * kSSC];     // 20,480 B : per-wave hi/lo scratch
    int tid = threadIdx.x;
    int wave = tid >> 6, lane = tid & 63;
    int r16 = lane & 15, quad = lane >> 4;
    int mt_raw = blockIdx.x * 8 + wave;
    int mt = (mt_raw < kN / 16) ? mt_raw : (kN / 16 - 1);
    int valid = (mt_raw < kN / 16);

    // ---- A1 fragments (16 rows, hi/lo split when f32) ----
    short8 ahi[10], alo[10];
    short8 zed = {0, 0, 0, 0, 0, 0, 0, 0};
    if (F32P) {
        const float* Arow = (const float*)A + (size_t)(mt * 16 + r16) * kSA + quad * 8;
#pragma unroll
        for (int kc = 0; kc < 10; ++kc) {
            short8 h = zed, l = zed;
            if (kc < 9 || quad < 2) {
                const float* pp = Arow + kc * 32;
#pragma unroll
                for (int j = 0; j < 8; ++j) {
                    float xv = pp[j];
                    u16 hb = f2bf(xv);
                    float resid = xv - bf2f(hb);
                    h[j] = (short)hb;
                    l[j] = (short)f2bf(resid);
                }
            }
            ahi[kc] = h; alo[kc] = l;
        }
    } else {
        const u16* Arow = (const u16*)A + (size_t)(mt * 16 + r16) * kSA + quad * 8;
#pragma unroll
        for (int kc = 0; kc < 9; ++kc) ahi[kc] = load8(Arow + kc * 32);
        ahi[9] = (quad < 2) ? load8(Arow + 9 * 32) : zed;
#pragma unroll
        for (int kc = 0; kc < 10; ++kc) alo[kc] = zed;
    }

    // ---- persistent GEMM2 accumulators ----
    float4v acc2[19];
#pragma unroll
    for (int i = 0; i < 19; ++i) acc2[i] = zed4();

    u16* sc_hi = &LSC[wave][0][0];
    u16* sc_lo = &LSC[wave][1][0];

    for (int s = 0; s < 19; ++s) {
        __syncthreads();   // previous iteration's LB1/LB2 readers done

        // ---- cooperative staging ----
        // B1T rows [32s, 32s+32) : contiguous 10240 u16 in global
        {
            const u16* gsrc = B1T + (size_t)(32 * s) * kKW1;
#pragma unroll
            for (int it = 0; it < 3; ++it) {
                int f = (tid + it * 512) * 8;
                if (f < 32 * 320) {
                    short8 v = load8(gsrc + f);
                    int row = f / 320;
                    int col = f - row * 320;
                    store8(&LB1[row * kSB1 + col], v);
                }
            }
            // B2T[:, 32s:32s+32) : 304 x 32
#pragma unroll
            for (int it = 0; it < 3; ++it) {
                int f = (tid + it * 512) * 8;
                if (f < 304 * 32) {
                    int n = f >> 5;
                    int col = f & 31;
                    short8 v = load8(B2T + (size_t)n * kNHP + s * 32 + col);
                    store8(&LB2[n * kSB2 + col], v);
                }
            }
        }
        __syncthreads();

        // ---- GEMM1 for nt1 = 2s, 2s+1 -> relu -> hi/lo scratch ----
#pragma unroll
        for (int t = 0; t < 2; ++t) {
            int nt1 = 2 * s + t;
            const u16* bb = &LB1[(t * 16 + r16) * kSB1 + quad * 8];
            float4v acc = zed4();
#pragma unroll
            for (int kc = 0; kc < 10; ++kc) {
                short8 b = load8(bb + kc * 32);
                acc = __builtin_amdgcn_mfma_f32_16x16x32_bf16(ahi[kc], b, acc, 0, 0, 0);
                if (F32P)
                    acc = __builtin_amdgcn_mfma_f32_16x16x32_bf16(alo[kc], b, acc, 0, 0, 0);
            }
            int n = nt1 * 16 + r16;              // h1 col = lane&15
            float bv = (n < kNH) ? bias1[n] : 0.f;
#pragma unroll
            for (int r = 0; r < 4; ++r) {        // h1 row-in-tile = quad*4 + r
                float v = acc[r] + bv;
                if (v < 0.f) v = 0.f;
                u16 hb = 0, lb = 0;
                if (n < kNH) {
                    hb = f2bf(v);
                    lb = f2bf(v - bf2f(hb));
                }
                sc_hi[(quad * 4 + r) * kSSC + t * 16 + r16] = hb;
                sc_lo[(quad * 4 + r) * kSSC + t * 16 + r16] = lb;
            }
        }
        // wave-private scratch: compiler inserts lgkmcnt wait before reads

        // ---- transpose read: A-layout frags for this 32-k-slice ----
        short8 a2h = load8(&sc_hi[r16 * kSSC + quad * 8]);
        short8 a2l = load8(&sc_lo[r16 * kSSC + quad * 8]);

        // ---- GEMM2 accumulate (k-slice s) ----
#pragma unroll
        for (int nt2 = 0; nt2 < 19; ++nt2) {
            short8 b = load8(&LB2[(nt2 * 16 + r16) * kSB2 + quad * 8]);
            acc2[nt2] = __builtin_amdgcn_mfma_f32_16x16x32_bf16(a2h, b, acc2[nt2], 0, 0, 0);
            acc2[nt2] = __builtin_amdgcn_mfma_f32_16x16x32_bf16(a2l, b, acc2[nt2], 0, 0, 0);
        }
    }

    // ---- epilogue: +bias2 -> D ----
    if (valid) {
#pragma unroll
        for (int nt2 = 0; nt2 < 19; ++nt2) {
            int n = nt2 * 16 + r16;
            if (n < kEMB) {
                float bv = bias2[n];
#pragma unroll
                for (int r = 0; r < 4; ++r) {
                    int m = mt * 16 + quad * 4 + r;
                    pwrite(D, (size_t)m * kSA + n, acc2[nt2][r] + bv, F32P);
                }
            }
        }
    }
}

// ---- BN stats: column sums / sumsq ----------------------------------------
__global__ __launch_bounds__(256) void bn_stats_kernel(
        const void* __restrict__ H2, float* __restrict__ stats, int f32p) {
    int row0 = blockIdx.x * 128;
    for (int c = threadIdx.x; c < kEMB; c += 256) {
        float s = 0.f, q = 0.f;
        for (int r = 0; r < 128; ++r) {
            int row = row0 + r;
            if (row < kN) {
                float v = pread(H2, (size_t)row * kSA + c, f32p);
                s += v; q += v * v;
            }
        }
        atomicAdd(&stats[c], s);
        atomicAdd(&stats[kEMB + c], q);
    }
}

// ---- per-graph mean pool with fused final BN (no relu) --------------------
__device__ inline int lower_bound(const int* a, int n, int key) {
    int lo = 0, hi = n;
    while (lo < hi) { int mid = (lo + hi) >> 1; if (a[mid] < key) lo = mid + 1; else hi = mid; }
    return lo;
}
__global__ __launch_bounds__(64) void pool_kernel(const void* __restrict__ h2,
                                                  const int* __restrict__ batch,
                                                  const float* __restrict__ stats,
                                                  const float* __restrict__ gam,
                                                  const float* __restrict__ bet,
                                                  void* __restrict__ out,
                                                  const int* __restrict__ flag, int f32p) {
    int g = blockIdx.x;
    int lane = threadIdx.x;
    int isf = *flag;
    int start = lower_bound(batch, kN, g);
    int end = lower_bound(batch, kN, g + 1);
    int cnt = end - start;
    float inv = 1.0f / (float)(cnt > 0 ? cnt : 1);
    for (int c = lane; c < kEMB; c += 64) {
        const float invM = 1.0f / kN;
        float mu = stats[c] * invM;
        float var = stats[kEMB + c] * invM - mu * mu;
        if (var < 0.f) var = 0.f;
        float rs = rsqrtf(var + kEPS);
        float sc = rs * gam[c];
        float sh = bet[c] - mu * sc;
        float s = 0.f;
        for (int n = start; n < end; ++n)
            s += pread(h2, (size_t)n * kSA + c, f32p) * sc + sh;
        float v = s * inv;
        if (isf) ((float*)out)[g * kEMB + c] = v;
        else     ((u16*)out)[g * kEMB + c] = f2bf(v);
    }
}

// ===========================================================================
extern "C" void kernel_launch(void* const* d_in, const int* in_sizes, int n_in,
                              void* d_out, int out_size, void* d_ws, size_t ws_size,
                              hipStream_t stream) {
    const int* x          = (const int*)d_in[0];
    const int* edge_index = (const int*)d_in[1];
    const int* edge_attr  = (const int*)d_in[2];
    const int* batch      = (const int*)d_in[3];
    const void* x_emb1 = d_in[4];
    const void* x_emb2 = d_in[5];
    const void* e1raw  = d_in[6];
    const void* e2raw  = d_in[7];
    const void* W1     = d_in[8];
    const void* b1raw  = d_in[9];
    const void* W2     = d_in[10];
    const void* b2raw  = d_in[11];
    const void* gmraw  = d_in[12];
    const void* btraw  = d_in[13];

    const int* src = edge_index;
    const int* dst = edge_index + kE;

    // Path select: big ws -> f32 feature planes (high precision path).
    const int f32p = (ws_size >= (size_t)250000000) ? 1 : 0;
    const size_t esz = f32p ? 4 : 2;

    // ---- carve workspace (256B aligned) ----
    char* p = (char*)d_ws;
    size_t off = 0;
    auto carve = [&](size_t bytes) {
        void* r = p + off;
        off += (bytes + 255) & ~(size_t)255;
        return r;
    };
    void* plane0 = carve((size_t)kN * kSA * esz);
    void* plane1 = carve((size_t)kN * kSA * esz);
    u16* W1T     = (u16*)carve((size_t)kL * kNHP * kKW1 * 2);
    u16* W2T     = (u16*)carve((size_t)kL * kNP2 * kNHP * 2);
    int* row_ptr = (int*)carve((size_t)(kN + 1) * 4);
    int* cursor  = (int*)carve((size_t)kN * 4);
    int* epack   = (int*)carve((size_t)kE * 4);
    float* stats = (float*)carve(2 * kEMB * 4);
    int* flag    = (int*)carve(256);
    float* parf  = (float*)carve((size_t)57900 * 4);   // canonical f32 params

    float* emb1  = parf + 0;       // 36000
    float* emb2  = parf + 36000;   // 900
    float* e1    = parf + 36900;   // 9000
    float* e2    = parf + 45900;   // 4500
    float* b1    = parf + 50400;   // 3000
    float* b2    = parf + 53400;   // 1500
    float* gamma = parf + 54900;   // 1500
    float* beta  = parf + 56400;   // 1500

    // ---- dtype detect + canonicalize params to f32 ----
    detect_kernel<<<1, 64, 0, stream>>>((const u16*)W1, flag);
    cvt_kernel<<<(36000 + 255) / 256, 256, 0, stream>>>(x_emb1, emb1, 36000, flag);
    cvt_kernel<<<(900 + 255) / 256, 256, 0, stream>>>(x_emb2, emb2, 900, flag);
    cvt_kernel<<<(9000 + 255) / 256, 256, 0, stream>>>(e1raw, e1, 9000, flag);
    cvt_kernel<<<(4500 + 255) / 256, 256, 0, stream>>>(e2raw, e2, 4500, flag);
    cvt_kernel<<<(3000 + 255) / 256, 256, 0, stream>>>(b1raw, b1, 3000, flag);
    cvt_kernel<<<(1500 + 255) / 256, 256, 0, stream>>>(b2raw, b2, 1500, flag);
    cvt_kernel<<<(1500 + 255) / 256, 256, 0, stream>>>(gmraw, gamma, 1500, flag);
    cvt_kernel<<<(1500 + 255) / 256, 256, 0, stream>>>(btraw, beta, 1500, flag);

    // ---- weight transpose/pad (bf16) ----
    {
        int n1 = kL * kNHP * kKW1;
        w1t_kernel<<<(n1 + 255) / 256, 256, 0, stream>>>(W1, W1T, flag);
        int n2 = kL * kNP2 * kNHP;
        w2t_kernel<<<(n2 + 255) / 256, 256, 0, stream>>>(W2, W2T, flag);
    }

    // ---- embedding into plane0 ----
    embed_kernel<<<(kN * kSA + 255) / 256, 256, 0, stream>>>(x, emb1, emb2, plane0, f32p);

    // ---- CSR build ----
    zero_int_kernel<<<(kN + 1 + 255) / 256, 256, 0, stream>>>(row_ptr, kN + 1);
    zero_int_kernel<<<(kN + 255) / 256, 256, 0, stream>>>(cursor, kN);
    count_kernel<<<(kE + 255) / 256, 256, 0, stream>>>(dst, row_ptr);
    scan_kernel<<<1, 1024, 0, stream>>>(row_ptr + 1, kN);
    scatter_kernel<<<(kE + 255) / 256, 256, 0, stream>>>(src, dst, edge_attr, row_ptr,
                                                         cursor, epack);

    // ---- layers ----
    const int mlp_blocks = (kN / 16 + 7) / 8;   // 782 (8 m-tiles per block)
    void* cur = plane0;
    void* agg = plane1;
    for (int l = 0; l < kL; ++l) {
        aggregate_kernel<<<(kN + 3) / 4, 256, 0, stream>>>(
            cur, row_ptr, epack, e1 + l * 6 * kEMB, e2 + l * 3 * kEMB,
            stats, gamma + (l > 0 ? (l - 1) : 0) * kEMB,
            beta + (l > 0 ? (l - 1) : 0) * kEMB, agg, (l > 0) ? 1 : 0, f32p);
        void* dout = f32p ? cur : agg;
        if (f32p)
            mlp_kernel<1><<<mlp_blocks, 512, 0, stream>>>(
                agg, dout, W1T + (size_t)l * kNHP * kKW1, b1 + l * kNH,
                W2T + (size_t)l * kNP2 * kNHP, b2 + l * kEMB);
        else
            mlp_kernel<0><<<mlp_blocks, 512, 0, stream>>>(
                agg, dout, W1T + (size_t)l * kNHP * kKW1, b1 + l * kNH,
                W2T + (size_t)l * kNP2 * kNHP, b2 + l * kEMB);
        zero_f32_kernel<<<(2 * kEMB + 255) / 256, 256, 0, stream>>>(stats, 2 * kEMB);
        bn_stats_kernel<<<(kN + 127) / 128, 256, 0, stream>>>(dout, stats, f32p);
        cur = dout;
        agg = (cur == plane0) ? plane1 : plane0;
    }

    // ---- pooling with fused final BN ----
    pool_kernel<<<kG, 64, 0, stream>>>(cur, batch, stats, gamma + 4 * kEMB,
                                       beta + 4 * kEMB, d_out, flag, f32p);
}

// Round 12
// 2462.103 us; speedup vs baseline: 1.7970x; 1.2040x over previous
//
#include <hip/hip_runtime.h>

typedef unsigned short u16;
typedef unsigned int u32;
typedef __attribute__((ext_vector_type(8))) short short8;
typedef __attribute__((ext_vector_type(4))) float float4v;

static constexpr int   kN    = 100000;   // nodes
static constexpr int   kE    = 200000;   // edges
static constexpr int   kEMB  = 300;
static constexpr int   kSA   = 304;      // feature row stride (elems)
static constexpr int   kKW1  = 320;      // W1T row stride (K padded)
static constexpr int   kNH   = 600;
static constexpr int   kNHP  = 608;
static constexpr int   kNP2  = 304;
static constexpr int   kG    = 5000;
static constexpr int   kL    = 5;
static constexpr float kEPS  = 1e-5f;

// mlp pipeline LDS strides
static constexpr int   kSB1  = 328;      // B1 slice row stride (u16): 164dw%32=4 -> uniform 8-start
static constexpr int   kSB2  = 40;       // B2 slice row stride (u16): 20dw%32=20 -> uniform 8-start
static constexpr int   kSSCW = 36;       // scratch row stride (u32): 36%32=4 -> 2-way only (free)

__device__ inline float bf2f(u16 u) {
    union { u32 u32v; float f; } v; v.u32v = ((u32)u) << 16; return v.f;
}
__device__ inline u16 f2bf(float f) {
    union { float f; u32 u; } v; v.f = f;
    u32 r = v.u + 0x7fff + ((v.u >> 16) & 1);
    return (u16)(r >> 16);
}
__device__ inline short8 load8(const u16* p) {
    return *reinterpret_cast<const short8*>(p);
}
__device__ inline void store8(u16* p, short8 v) {
    *reinterpret_cast<short8*>(p) = v;
}
__device__ inline float4v zed4() { float4v z = {0.f, 0.f, 0.f, 0.f}; return z; }
__device__ inline float gload(const void* p, long long i, int isf32) {
    if (isf32) return ((const float*)p)[i];
    return bf2f(((const u16*)p)[i]);
}
__device__ inline float pread(const void* p, size_t i, int f32p) {
    if (f32p) return ((const float*)p)[i];
    return bf2f(((const u16*)p)[i]);
}
__device__ inline void pwrite(void* p, size_t i, float v, int f32p) {
    if (f32p) ((float*)p)[i] = v;
    else      ((u16*)p)[i] = f2bf(v);
}

// ---- dtype detect: vote on W1 bit patterns --------------------------------
__global__ void detect_kernel(const u16* __restrict__ w1raw, int* flag) {
    if (threadIdx.x == 0 && blockIdx.x == 0) {
        int cnt = 0;
        for (int i = 0; i < 256; ++i) {
            int e = (w1raw[i] >> 7) & 0xFF;
            if (e >= 96 && e <= 126) ++cnt;
        }
        *flag = (cnt >= 200) ? 0 : 1;                // 0 = bf16 inputs, 1 = f32
    }
}

// ---- convert a float input to canonical f32 -------------------------------
__global__ void cvt_kernel(const void* __restrict__ src, float* __restrict__ dst,
                           int n, const int* __restrict__ flag) {
    int i = blockIdx.x * blockDim.x + threadIdx.x;
    if (i >= n) return;
    int isf = *flag;
    dst[i] = isf ? ((const float*)src)[i] : bf2f(((const u16*)src)[i]);
}

// ---- weight transpose + pad (bf16 out; writes every element) --------------
__global__ void w1t_kernel(const void* __restrict__ W1, u16* __restrict__ W1T,
                           const int* __restrict__ flag) {
    int idx = blockIdx.x * blockDim.x + threadIdx.x;
    const int per_layer = kNHP * kKW1;
    if (idx >= kL * per_layer) return;
    int isf = *flag;
    int l = idx / per_layer; int rem = idx - l * per_layer;
    int n = rem / kKW1; int k = rem - n * kKW1;
    u16 v = 0;
    if (n < kNH && k < kEMB)
        v = f2bf(gload(W1, (long long)l * kEMB * kNH + (long long)k * kNH + n, isf));
    W1T[idx] = v;
}
__global__ void w2t_kernel(const void* __restrict__ W2, u16* __restrict__ W2T,
                           const int* __restrict__ flag) {
    int idx = blockIdx.x * blockDim.x + threadIdx.x;
    const int per_layer = kNP2 * kNHP;
    if (idx >= kL * per_layer) return;
    int isf = *flag;
    int l = idx / per_layer; int rem = idx - l * per_layer;
    int n = rem / kNHP; int k = rem - n * kNHP;
    u16 v = 0;
    if (n < kEMB && k < kNH)
        v = f2bf(gload(W2, (long long)l * kNH * kEMB + (long long)k * kEMB + n, isf));
    W2T[idx] = v;
}

// ---- embedding: h = emb1[x0] + emb2[x1] -> plane --------------------------
__global__ void embed_kernel(const int* __restrict__ x,
                             const float* __restrict__ emb1,
                             const float* __restrict__ emb2,
                             void* __restrict__ h, int f32p) {
    int idx = blockIdx.x * blockDim.x + threadIdx.x;
    if (idx >= kN * kSA) return;
    int n = idx / kSA; int c = idx - n * kSA;
    float v = 0.f;
    if (c < kEMB) v = emb1[x[2 * n] * kEMB + c] + emb2[x[2 * n + 1] * kEMB + c];
    pwrite(h, idx, v, f32p);
}

// ---- CSR build ------------------------------------------------------------
__global__ void zero_int_kernel(int* p, int n) {
    int i = blockIdx.x * blockDim.x + threadIdx.x;
    if (i < n) p[i] = 0;
}
__global__ void zero_f32_kernel(float* p, int n) {
    int i = blockIdx.x * blockDim.x + threadIdx.x;
    if (i < n) p[i] = 0.f;
}
__global__ void count_kernel(const int* __restrict__ dst, int* row_ptr) {
    int e = blockIdx.x * blockDim.x + threadIdx.x;
    if (e < kE) atomicAdd(&row_ptr[1 + dst[e]], 1);
}
__global__ __launch_bounds__(1024) void scan_kernel(int* a, int n) {
    __shared__ int s[1024];
    __shared__ int carry;
    int t = threadIdx.x;
    if (t == 0) carry = 0;
    __syncthreads();
    for (int base = 0; base < n; base += 1024) {
        int i = base + t;
        s[t] = (i < n) ? a[i] : 0;
        __syncthreads();
        for (int off = 1; off < 1024; off <<= 1) {
            int v = (t >= off) ? s[t - off] : 0;
            __syncthreads();
            s[t] += v;
            __syncthreads();
        }
        if (i < n) a[i] = s[t] + carry;
        __syncthreads();
        if (t == 1023) carry += s[1023];
        __syncthreads();
    }
}
__global__ void scatter_kernel(const int* __restrict__ src, const int* __restrict__ dst,
                               const int* __restrict__ ea,
                               const int* __restrict__ row_ptr, int* cursor,
                               int* __restrict__ epack) {
    int e = blockIdx.x * blockDim.x + threadIdx.x;
    if (e >= kE) return;
    int d = dst[e];
    int pos = row_ptr[d] + atomicAdd(&cursor[d], 1);
    epack[pos] = src[e] | (ea[2 * e] << 20) | (ea[2 * e + 1] << 24);
}

// ---- BN coefficient hoist: sc/sh per column (same f32 math as before) -----
__global__ void bn_coef_kernel(const float* __restrict__ stats,
                               const float* __restrict__ gam,
                               const float* __restrict__ bet,
                               float* __restrict__ coef) {
    int c = blockIdx.x * blockDim.x + threadIdx.x;
    if (c >= kEMB) return;
    const float invM = 1.0f / kN;
    float mu = stats[c] * invM;
    float var = stats[kEMB + c] * invM - mu * mu;
    if (var < 0.f) var = 0.f;
    float rs = rsqrtf(var + kEPS);
    float sc = rs * gam[c];
    coef[c] = sc;
    coef[kEMB + c] = bet[c] - mu * sc;
}

// ---- aggregation with fused BN(+relu) input transform ---------------------
__global__ __launch_bounds__(256) void aggregate_kernel(
        const void* __restrict__ h, const int* __restrict__ row_ptr,
        const int* __restrict__ epack,
        const float* __restrict__ e1,    // [6][kEMB] layer slice (f32)
        const float* __restrict__ e2,    // [3][kEMB]
        const float* __restrict__ coef,  // [2][kEMB] sc/sh (mode=1)
        void* __restrict__ agg, int mode, int f32p) {
    int wave = threadIdx.x >> 6;
    int lane = threadIdx.x & 63;
    int node = blockIdx.x * 4 + wave;
    if (node >= kN) return;

    float sc[5], sh[5], acc[5];
#pragma unroll
    for (int j = 0; j < 5; ++j) {
        int c = j * 64 + lane;
        sc[j] = 1.f; sh[j] = 0.f;
        if (mode && c < kEMB) {
            sc[j] = coef[c];
            sh[j] = coef[kEMB + c];
        }
        acc[j] = 0.f;
        if (c < kEMB) {
            float hv = pread(h, (size_t)node * kSA + c, f32p) * sc[j] + sh[j];
            if (mode && hv < 0.f) hv = 0.f;
            acc[j] = hv + e1[c] + e2[c];             // self loop ea=(0,0)
        }
    }
    int s = row_ptr[node], e = row_ptr[node + 1];
    for (int i = s; i < e; ++i) {
        int p = epack[i];
        int srcn = p & 0xFFFFF;
        int a0 = (p >> 20) & 15;
        int a1 = (p >> 24) & 15;
#pragma unroll
        for (int j = 0; j < 5; ++j) {
            int c = j * 64 + lane;
            if (c < kEMB) {
                float w = pread(h, (size_t)srcn * kSA + c, f32p) * sc[j] + sh[j];
                if (mode && w < 0.f) w = 0.f;
                acc[j] += w + e1[a0 * kEMB + c] + e2[a1 * kEMB + c];
            }
        }
    }
#pragma unroll
    for (int j = 0; j < 5; ++j) {
        int c = j * 64 + lane;
        if (c < kSA)
            pwrite(agg, (size_t)node * kSA + c, (c < kEMB) ? acc[j] : 0.f, f32p);
    }
}

// ---- fused MLP, k-slice pipeline v2: relu(A@W1+b1)@W2+b2 -> D -------------
// vs r11: (1) scratch hi/lo packed into one u32 (ds_write_b32, stride 36dw ->
// clean 2-way banking; r11's 16 scalar u16 writes had same-word conflicts ->
// 21.75M conflict cycles); (2) software-pipelined staging: global loads for
// slice s+1 issue into registers before compute of slice s -> L2 latency
// hidden behind GEMM work instead of stalling the barrier.  MFMA order per
// accumulator unchanged -> bit-identical output.
template <int F32P>
__global__ __launch_bounds__(512, 2) void mlp_kernel(
        const void* A, void* D,           // may alias (small-ws): no restrict
        const u16* __restrict__ B1T,      // [kNHP][kKW1] bf16, zero-padded
        const float* __restrict__ bias1,  // [kNH] f32
        const u16* __restrict__ B2T,      // [kNP2][kNHP] bf16, zero-padded
        const float* __restrict__ bias2) {// [kEMB] f32
    __shared__ u16 LB1[32 * kSB1];           // 20,992 B : B1T rows [32s,32s+32)
    __shared__ u16 LB2[304 * kSB2];          // 24,320 B : B2T cols [32s,32s+32)
    __shared__ u32 LSC[8][16 * kSSCW];       // 18,432 B : per-wave packed hi|lo
    int tid = threadIdx.x;
    int wave = tid >> 6, lane = tid & 63;
    int r16 = lane & 15, quad = lane >> 4;
    int mt_raw = blockIdx.x * 8 + wave;
    int mt = (mt_raw < kN / 16) ? mt_raw : (kN / 16 - 1);
    int valid = (mt_raw < kN / 16);

    // ---- A1 fragments (16 rows, hi/lo split when f32) ----
    short8 ahi[10], alo[10];
    short8 zed = {0, 0, 0, 0, 0, 0, 0, 0};
    if (F32P) {
        const float* Arow = (const float*)A + (size_t)(mt * 16 + r16) * kSA + quad * 8;
#pragma unroll
        for (int kc = 0; kc < 10; ++kc) {
            short8 h = zed, l = zed;
            if (kc < 9 || quad < 2) {
                const float* pp = Arow + kc * 32;
#pragma unroll
                for (int j = 0; j < 8; ++j) {
                    float xv = pp[j];
                    u16 hb = f2bf(xv);
                    float resid = xv - bf2f(hb);
                    h[j] = (short)hb;
                    l[j] = (short)f2bf(resid);
                }
            }
            ahi[kc] = h; alo[kc] = l;
        }
    } else {
        const u16* Arow = (const u16*)A + (size_t)(mt * 16 + r16) * kSA + quad * 8;
#pragma unroll
        for (int kc = 0; kc < 9; ++kc) ahi[kc] = load8(Arow + kc * 32);
        ahi[9] = (quad < 2) ? load8(Arow + 9 * 32) : zed;
#pragma unroll
        for (int kc = 0; kc < 10; ++kc) alo[kc] = zed;
    }

    // ---- persistent GEMM2 accumulators ----
    float4v acc2[19];
#pragma unroll
    for (int i = 0; i < 19; ++i) acc2[i] = zed4();

    u32* sc = &LSC[wave][0];

    // ---- staging registers + load/write helpers ----
    short8 st1[3], st2[3];
#pragma unroll
    for (int it = 0; it < 3; ++it) { st1[it] = zed; st2[it] = zed; }
    auto stage_load = [&](int s) {
#pragma unroll
        for (int it = 0; it < 3; ++it) {
            int f = (tid + it * 512) * 8;
            if (f < 32 * 320)
                st1[it] = load8(B1T + (size_t)(32 * s) * kKW1 + f);
        }
#pragma unroll
        for (int it = 0; it < 3; ++it) {
            int f = (tid + it * 512) * 8;
            if (f < 304 * 32) {
                int n = f >> 5, col = f & 31;
                st2[it] = load8(B2T + (size_t)n * kNHP + s * 32 + col);
            }
        }
    };
    auto stage_write = [&]() {
#pragma unroll
        for (int it = 0; it < 3; ++it) {
            int f = (tid + it * 512) * 8;
            if (f < 32 * 320) {
                int row = f / 320, col = f - row * 320;
                store8(&LB1[row * kSB1 + col], st1[it]);
            }
        }
#pragma unroll
        for (int it = 0; it < 3; ++it) {
            int f = (tid + it * 512) * 8;
            if (f < 304 * 32) {
                int n = f >> 5, col = f & 31;
                store8(&LB2[n * kSB2 + col], st2[it]);
            }
        }
    };

    stage_load(0);
    for (int s = 0; s < 19; ++s) {
        __syncthreads();   // prior slice's LB1/LB2 readers done
        stage_write();     // vmcnt wait here: loads issued one compute-phase ago
        __syncthreads();
        if (s + 1 < 19) stage_load(s + 1);   // overlap with compute below

        // ---- GEMM1 for nt1 = 2s, 2s+1 -> relu -> packed scratch ----
#pragma unroll
        for (int t = 0; t < 2; ++t) {
            const u16* bb = &LB1[(t * 16 + r16) * kSB1 + quad * 8];
            float4v acc = zed4();
#pragma unroll
            for (int kc = 0; kc < 10; ++kc) {
                short8 b = load8(bb + kc * 32);
                acc = __builtin_amdgcn_mfma_f32_16x16x32_bf16(ahi[kc], b, acc, 0, 0, 0);
                if (F32P)
                    acc = __builtin_amdgcn_mfma_f32_16x16x32_bf16(alo[kc], b, acc, 0, 0, 0);
            }
            int n = (2 * s + t) * 16 + r16;      // h1 col = lane&15
            float bv = (n < kNH) ? bias1[n] : 0.f;
#pragma unroll
            for (int r = 0; r < 4; ++r) {        // h1 row-in-tile = quad*4 + r
                float v = acc[r] + bv;
                if (v < 0.f) v = 0.f;
                u32 pk = 0;
                if (n < kNH) {
                    u16 hb = f2bf(v);
                    u16 lb = f2bf(v - bf2f(hb));
                    pk = (u32)hb | ((u32)lb << 16);
                }
                sc[(quad * 4 + r) * kSSCW + t * 16 + r16] = pk;
            }
        }
        // wave-private scratch: compiler inserts lgkmcnt wait before reads

        // ---- transpose read + unpack: A-layout frags for this k-slice ----
        u32 w0[8];
#pragma unroll
        for (int j = 0; j < 8; ++j) w0[j] = sc[r16 * kSSCW + quad * 8 + j];
        short8 a2h, a2l;
#pragma unroll
        for (int j = 0; j < 8; ++j) {
            a2h[j] = (short)(w0[j] & 0xFFFFu);
            a2l[j] = (short)(w0[j] >> 16);
        }

        // ---- GEMM2 accumulate (k-slice s) ----
#pragma unroll
        for (int nt2 = 0; nt2 < 19; ++nt2) {
            short8 b = load8(&LB2[(nt2 * 16 + r16) * kSB2 + quad * 8]);
            acc2[nt2] = __builtin_amdgcn_mfma_f32_16x16x32_bf16(a2h, b, acc2[nt2], 0, 0, 0);
            acc2[nt2] = __builtin_amdgcn_mfma_f32_16x16x32_bf16(a2l, b, acc2[nt2], 0, 0, 0);
        }
    }

    // ---- epilogue: +bias2 -> D ----
    if (valid) {
#pragma unroll
        for (int nt2 = 0; nt2 < 19; ++nt2) {
            int n = nt2 * 16 + r16;
            if (n < kEMB) {
                float bv = bias2[n];
#pragma unroll
                for (int r = 0; r < 4; ++r) {
                    int m = mt * 16 + quad * 4 + r;
                    pwrite(D, (size_t)m * kSA + n, acc2[nt2][r] + bv, F32P);
                }
            }
        }
    }
}

// ---- BN stats: column sums / sumsq ----------------------------------------
__global__ __launch_bounds__(256) void bn_stats_kernel(
        const void* __restrict__ H2, float* __restrict__ stats, int f32p) {
    int row0 = blockIdx.x * 128;
    for (int c = threadIdx.x; c < kEMB; c += 256) {
        float s = 0.f, q = 0.f;
        for (int r = 0; r < 128; ++r) {
            int row = row0 + r;
            if (row < kN) {
                float v = pread(H2, (size_t)row * kSA + c, f32p);
                s += v; q += v * v;
            }
        }
        atomicAdd(&stats[c], s);
        atomicAdd(&stats[kEMB + c], q);
    }
}

// ---- per-graph mean pool with fused final BN (no relu) --------------------
__device__ inline int lower_bound(const int* a, int n, int key) {
    int lo = 0, hi = n;
    while (lo < hi) { int mid = (lo + hi) >> 1; if (a[mid] < key) lo = mid + 1; else hi = mid; }
    return lo;
}
__global__ __launch_bounds__(64) void pool_kernel(const void* __restrict__ h2,
                                                  const int* __restrict__ batch,
                                                  const float* __restrict__ stats,
                                                  const float* __restrict__ gam,
                                                  const float* __restrict__ bet,
                                                  void* __restrict__ out,
                                                  const int* __restrict__ flag, int f32p) {
    int g = blockIdx.x;
    int lane = threadIdx.x;
    int isf = *flag;
    int start = lower_bound(batch, kN, g);
    int end = lower_bound(batch, kN, g + 1);
    int cnt = end - start;
    float inv = 1.0f / (float)(cnt > 0 ? cnt : 1);
    for (int c = lane; c < kEMB; c += 64) {
        const float invM = 1.0f / kN;
        float mu = stats[c] * invM;
        float var = stats[kEMB + c] * invM - mu * mu;
        if (var < 0.f) var = 0.f;
        float rs = rsqrtf(var + kEPS);
        float sc = rs * gam[c];
        float sh = bet[c] - mu * sc;
        float s = 0.f;
        for (int n = start; n < end; ++n)
            s += pread(h2, (size_t)n * kSA + c, f32p) * sc + sh;
        float v = s * inv;
        if (isf) ((float*)out)[g * kEMB + c] = v;
        else     ((u16*)out)[g * kEMB + c] = f2bf(v);
    }
}

// ===========================================================================
extern "C" void kernel_launch(void* const* d_in, const int* in_sizes, int n_in,
                              void* d_out, int out_size, void* d_ws, size_t ws_size,
                              hipStream_t stream) {
    const int* x          = (const int*)d_in[0];
    const int* edge_index = (const int*)d_in[1];
    const int* edge_attr  = (const int*)d_in[2];
    const int* batch      = (const int*)d_in[3];
    const void* x_emb1 = d_in[4];
    const void* x_emb2 = d_in[5];
    const void* e1raw  = d_in[6];
    const void* e2raw  = d_in[7];
    const void* W1     = d_in[8];
    const void* b1raw  = d_in[9];
    const void* W2     = d_in[10];
    const void* b2raw  = d_in[11];
    const void* gmraw  = d_in[12];
    const void* btraw  = d_in[13];

    const int* src = edge_index;
    const int* dst = edge_index + kE;

    // Path select: big ws -> f32 feature planes (high precision path).
    const int f32p = (ws_size >= (size_t)250000000) ? 1 : 0;
    const size_t esz = f32p ? 4 : 2;

    // ---- carve workspace (256B aligned) ----
    char* p = (char*)d_ws;
    size_t off = 0;
    auto carve = [&](size_t bytes) {
        void* r = p + off;
        off += (bytes + 255) & ~(size_t)255;
        return r;
    };
    void* plane0 = carve((size_t)kN * kSA * esz);
    void* plane1 = carve((size_t)kN * kSA * esz);
    u16* W1T     = (u16*)carve((size_t)kL * kNHP * kKW1 * 2);
    u16* W2T     = (u16*)carve((size_t)kL * kNP2 * kNHP * 2);
    int* row_ptr = (int*)carve((size_t)(kN + 1) * 4);
    int* cursor  = (int*)carve((size_t)kN * 4);
    int* epack   = (int*)carve((size_t)kE * 4);
    float* stats = (float*)carve(2 * kEMB * 4);
    float* coef  = (float*)carve(2 * kEMB * 4);
    int* flag    = (int*)carve(256);
    float* parf  = (float*)carve((size_t)57900 * 4);   // canonical f32 params

    float* emb1  = parf + 0;       // 36000
    float* emb2  = parf + 36000;   // 900
    float* e1    = parf + 36900;   // 9000
    float* e2    = parf + 45900;   // 4500
    float* b1    = parf + 50400;   // 3000
    float* b2    = parf + 53400;   // 1500
    float* gamma = parf + 54900;   // 1500
    float* beta  = parf + 56400;   // 1500

    // ---- dtype detect + canonicalize params to f32 ----
    detect_kernel<<<1, 64, 0, stream>>>((const u16*)W1, flag);
    cvt_kernel<<<(36000 + 255) / 256, 256, 0, stream>>>(x_emb1, emb1, 36000, flag);
    cvt_kernel<<<(900 + 255) / 256, 256, 0, stream>>>(x_emb2, emb2, 900, flag);
    cvt_kernel<<<(9000 + 255) / 256, 256, 0, stream>>>(e1raw, e1, 9000, flag);
    cvt_kernel<<<(4500 + 255) / 256, 256, 0, stream>>>(e2raw, e2, 4500, flag);
    cvt_kernel<<<(3000 + 255) / 256, 256, 0, stream>>>(b1raw, b1, 3000, flag);
    cvt_kernel<<<(1500 + 255) / 256, 256, 0, stream>>>(b2raw, b2, 1500, flag);
    cvt_kernel<<<(1500 + 255) / 256, 256, 0, stream>>>(gmraw, gamma, 1500, flag);
    cvt_kernel<<<(1500 + 255) / 256, 256, 0, stream>>>(btraw, beta, 1500, flag);

    // ---- weight transpose/pad (bf16) ----
    {
        int n1 = kL * kNHP * kKW1;
        w1t_kernel<<<(n1 + 255) / 256, 256, 0, stream>>>(W1, W1T, flag);
        int n2 = kL * kNP2 * kNHP;
        w2t_kernel<<<(n2 + 255) / 256, 256, 0, stream>>>(W2, W2T, flag);
    }

    // ---- embedding into plane0 ----
    embed_kernel<<<(kN * kSA + 255) / 256, 256, 0, stream>>>(x, emb1, emb2, plane0, f32p);

    // ---- CSR build ----
    zero_int_kernel<<<(kN + 1 + 255) / 256, 256, 0, stream>>>(row_ptr, kN + 1);
    zero_int_kernel<<<(kN + 255) / 256, 256, 0, stream>>>(cursor, kN);
    count_kernel<<<(kE + 255) / 256, 256, 0, stream>>>(dst, row_ptr);
    scan_kernel<<<1, 1024, 0, stream>>>(row_ptr + 1, kN);
    scatter_kernel<<<(kE + 255) / 256, 256, 0, stream>>>(src, dst, edge_attr, row_ptr,
                                                         cursor, epack);

    // ---- layers ----
    const int mlp_blocks = (kN / 16 + 7) / 8;   // 782 (8 m-tiles per block)
    void* cur = plane0;
    void* agg = plane1;
    for (int l = 0; l < kL; ++l) {
        aggregate_kernel<<<(kN + 3) / 4, 256, 0, stream>>>(
            cur, row_ptr, epack, e1 + l * 6 * kEMB, e2 + l * 3 * kEMB,
            coef, agg, (l > 0) ? 1 : 0, f32p);
        void* dout = f32p ? cur : agg;
        if (f32p)
            mlp_kernel<1><<<mlp_blocks, 512, 0, stream>>>(
                agg, dout, W1T + (size_t)l * kNHP * kKW1, b1 + l * kNH,
                W2T + (size_t)l * kNP2 * kNHP, b2 + l * kEMB);
        else
            mlp_kernel<0><<<mlp_blocks, 512, 0, stream>>>(
                agg, dout, W1T + (size_t)l * kNHP * kKW1, b1 + l * kNH,
                W2T + (size_t)l * kNP2 * kNHP, b2 + l * kEMB);
        zero_f32_kernel<<<(2 * kEMB + 255) / 256, 256, 0, stream>>>(stats, 2 * kEMB);
        bn_stats_kernel<<<(kN + 127) / 128, 256, 0, stream>>>(dout, stats, f32p);
        bn_coef_kernel<<<(kEMB + 255) / 256, 256, 0, stream>>>(
            stats, gamma + l * kEMB, beta + l * kEMB, coef);
        cur = dout;
        agg = (cur == plane0) ? plane1 : plane0;
    }

    // ---- pooling with fused final BN ----
    pool_kernel<<<kG, 64, 0, stream>>>(cur, batch, stats, gamma + 4 * kEMB,
                                       beta + 4 * kEMB, d_out, flag, f32p);
}